// Round 9
// baseline (627.935 us; speedup 1.0000x reference)
//
#include <hip/hip_runtime.h>
#include <hip/hip_bf16.h>
#include <stdint.h>

#define N_USERS 100000
#define N_ITEMS 50000
#define DIM     64
#define QDIM    5
#define NNZ     1000000
#define BATCH   1024
#define HALF_NNZ (NNZ/2)

#define RB      128                       // rows per bucket
#define NBKT_U  ((N_USERS + RB - 1) / RB) // 782
#define NBKT_I  ((N_ITEMS + RB - 1) / RB) // 391
#define NBLK    256                       // partition blocks
#define EPB2    ((HALF_NNZ + NBLK - 1) / NBLK) // 1954 edge-PAIRS per block
#define SC_E    4096                      // elements per scan block (256 thr x 16)
#define N2D_U   (NBKT_U * NBLK)           // 200192
#define N2D_I   (NBKT_I * NBLK)           // 100096
#define NBU     ((N2D_U + SC_E - 1) / SC_E) // 49
#define NBI     ((N2D_I + SC_E - 1) / SC_E) // 25
#define UBLK    (N_USERS * 64 / 256)      // 25000 user spmm blocks
#define CSCAP   3072                      // csort LDS edge capacity (24 KB)

typedef __hip_bfloat16 bf16;
typedef __attribute__((ext_vector_type(8))) short bf16x8;
typedef __attribute__((ext_vector_type(4))) float f32x4;

// scalar accumulator slots: [0]=sumsq [1]=posu [2]=posi [3]=bpr [4]=nlu [5]=nli
#define SC_SUMSQ 0
#define SC_POSU  1
#define SC_POSI  2
#define SC_BPR   3
#define SC_NLU   4
#define SC_NLI   5

// ---------------- threefry2x32 (exact JAX block) ----------------
__host__ __device__ inline void tf2x32(uint32_t k0, uint32_t k1,
                                       uint32_t x0, uint32_t x1,
                                       uint32_t& o0, uint32_t& o1) {
  uint32_t ks2 = k0 ^ k1 ^ 0x1BD11BDAu;
  x0 += k0; x1 += k1;
#define TF_R(r) { x0 += x1; x1 = (x1 << (r)) | (x1 >> (32 - (r))); x1 ^= x0; }
  TF_R(13) TF_R(15) TF_R(26) TF_R(6)
  x0 += k1; x1 += ks2 + 1u;
  TF_R(17) TF_R(29) TF_R(16) TF_R(24)
  x0 += ks2; x1 += k0 + 2u;
  TF_R(13) TF_R(15) TF_R(26) TF_R(6)
  x0 += k0; x1 += k1 + 3u;
  TF_R(17) TF_R(29) TF_R(16) TF_R(24)
  x0 += k1; x1 += ks2 + 4u;
  TF_R(13) TF_R(15) TF_R(26) TF_R(6)
  x0 += ks2; x1 += k0 + 5u;
#undef TF_R
  o0 = x0; o1 = x1;
}

__device__ __forceinline__ float mask_from_bits(uint32_t bits) {
  float f = __uint_as_float((bits >> 9) | 0x3f800000u) - 1.0f;
  return (f < 0.75f) ? (1.0f / 0.75f) : 0.0f;
}

__device__ __forceinline__ uint32_t f2bfbits(float f) {
  bf16 h = __float2bfloat16(f);
  return (uint32_t)(*reinterpret_cast<unsigned short*>(&h));
}

// ---------------- bucket counting (edge pairs, matches k_part) ----------------
__global__ __launch_bounds__(256) void k_bcount(const int* __restrict__ rows,
                                                const int* __restrict__ cols,
                                                int* __restrict__ cnt_u,
                                                int* __restrict__ cnt_i) {
  __shared__ int hu[NBKT_U];
  __shared__ int hv[NBKT_I];
  for (int i = threadIdx.x; i < NBKT_U; i += 256) hu[i] = 0;
  for (int i = threadIdx.x; i < NBKT_I; i += 256) hv[i] = 0;
  __syncthreads();
  int beg = blockIdx.x * EPB2, end = min(beg + EPB2, HALF_NNZ);
  for (int i = beg + threadIdx.x; i < end; i += 256) {
    atomicAdd(&hu[rows[i] >> 7], 1);
    atomicAdd(&hu[rows[i + HALF_NNZ] >> 7], 1);
    atomicAdd(&hv[cols[i] >> 7], 1);
    atomicAdd(&hv[cols[i + HALF_NNZ] >> 7], 1);
  }
  __syncthreads();
  for (int i = threadIdx.x; i < NBKT_U; i += 256) cnt_u[i * NBLK + blockIdx.x] = hu[i];
  for (int i = threadIdx.x; i < NBKT_I; i += 256) cnt_i[i * NBLK + blockIdx.x] = hv[i];
}

// ---------------- merged hierarchical scan (user + item) ----------------
__global__ __launch_bounds__(256) void k_bsum2(const int* __restrict__ cnt_u,
                                               const int* __restrict__ cnt_i,
                                               int* __restrict__ bsum_u,
                                               int* __restrict__ bsum_i) {
  const int* cnt; int n, b; int* bsum;
  if (blockIdx.x < NBU) { cnt = cnt_u; n = N2D_U; b = blockIdx.x; bsum = bsum_u; }
  else { cnt = cnt_i; n = N2D_I; b = blockIdx.x - NBU; bsum = bsum_i; }
  int base = b * SC_E + threadIdx.x * 16;
  int s = 0;
#pragma unroll
  for (int j = 0; j < 16; ++j) { int i = base + j; if (i < n) s += cnt[i]; }
  for (int off = 32; off; off >>= 1) s += __shfl_down(s, off);
  __shared__ int ws[4];
  if ((threadIdx.x & 63) == 0) ws[threadIdx.x >> 6] = s;
  __syncthreads();
  if (threadIdx.x == 0) bsum[b] = ws[0] + ws[1] + ws[2] + ws[3];
}

__global__ __launch_bounds__(64) void k_bscan2(const int* __restrict__ bsum_u,
                                               const int* __restrict__ bsum_i,
                                               int* __restrict__ boff_u,
                                               int* __restrict__ boff_i) {
  const int* bsum; int nb; int* boff;
  if (blockIdx.x == 0) { bsum = bsum_u; nb = NBU; boff = boff_u; }
  else { bsum = bsum_i; nb = NBI; boff = boff_i; }
  int lane = threadIdx.x;
  int v = (lane < nb) ? bsum[lane] : 0;
  int incl = v;
  for (int off = 1; off < 64; off <<= 1) {
    int t = __shfl_up(incl, off);
    if (lane >= off) incl += t;
  }
  if (lane < nb) boff[lane] = incl - v;
}

// in-place exclusive scan (ptr aliases cnt; per-thread chunks disjoint)
__global__ __launch_bounds__(256) void k_scan32(int* __restrict__ cnt_u,
                                                int* __restrict__ cnt_i,
                                                const int* __restrict__ boff_u,
                                                const int* __restrict__ boff_i) {
  int* cnt; int n, b; const int* boff;
  if (blockIdx.x < NBU) { cnt = cnt_u; n = N2D_U; b = blockIdx.x; boff = boff_u; }
  else { cnt = cnt_i; n = N2D_I; b = blockIdx.x - NBU; boff = boff_i; }
  int base = b * SC_E + threadIdx.x * 16;
  int c[16]; int s = 0;
#pragma unroll
  for (int j = 0; j < 16; ++j) { int i = base + j; c[j] = (i < n) ? cnt[i] : 0; s += c[j]; }
  int lane = threadIdx.x & 63, wid = threadIdx.x >> 6;
  int incl = s;
  for (int off = 1; off < 64; off <<= 1) {
    int t = __shfl_up(incl, off);
    if (lane >= off) incl += t;
  }
  __shared__ int wsum[4];
  if (lane == 63) wsum[wid] = incl;
  __syncthreads();
  int wpre = 0;
  for (int k = 0; k < wid; ++k) wpre += wsum[k];
  int run = boff[b] + wpre + (incl - s);
#pragma unroll
  for (int j = 0; j < 16; ++j) {
    int i = base + j;
    if (i < n) { cnt[i] = run; run += c[j]; }
  }
}

// ---------------- partition (edge pairs: both threefry outputs used) ----------
// payload int2: x = (local_row<<17)|col17, y = (bf16(v_layer1)<<16)|bf16(v_layer0)
__global__ __launch_bounds__(256) void k_part(const int* __restrict__ rows,
                                              const int* __restrict__ cols,
                                              const float* __restrict__ adj_vals,
                                              const int* __restrict__ off_u,
                                              const int* __restrict__ off_i,
                                              int2* __restrict__ ep_u,
                                              int2* __restrict__ ep_i,
                                              uint32_t a0, uint32_t a1,
                                              uint32_t b0, uint32_t b1,
                                              uint32_t c0, uint32_t c1,
                                              uint32_t d0, uint32_t d1) {
  __shared__ int cu[NBKT_U];
  __shared__ int ci[NBKT_I];
  for (int i = threadIdx.x; i < NBKT_U; i += 256) cu[i] = off_u[i * NBLK + blockIdx.x];
  for (int i = threadIdx.x; i < NBKT_I; i += 256) ci[i] = off_i[i * NBLK + blockIdx.x];
  __syncthreads();
  int beg = blockIdx.x * EPB2, end = min(beg + EPB2, HALF_NNZ);
  for (int i = beg + threadIdx.x; i < end; i += 256) {
    int e2 = i + HALF_NNZ;
    int rA = rows[i], cA = cols[i];
    int rB = rows[e2], cB = cols[e2];
    float vA = adj_vals[i], vB = adj_vals[e2];
    uint32_t mA0, mA1, mB0, mB1, mC0, mC1, mD0, mD1;
    tf2x32(a0, a1, (uint32_t)i, (uint32_t)e2, mA0, mA1);  // user L0
    tf2x32(b0, b1, (uint32_t)i, (uint32_t)e2, mB0, mB1);  // user L1
    tf2x32(c0, c1, (uint32_t)i, (uint32_t)e2, mC0, mC1);  // item L0
    tf2x32(d0, d1, (uint32_t)i, (uint32_t)e2, mD0, mD1);  // item L1
    // edge i
    {
      uint32_t u0 = f2bfbits(vA * mask_from_bits(mA0));
      uint32_t u1 = f2bfbits(vA * mask_from_bits(mB0));
      uint32_t i0 = f2bfbits(vA * mask_from_bits(mC0));
      uint32_t i1 = f2bfbits(vA * mask_from_bits(mD0));
      int pu = atomicAdd(&cu[rA >> 7], 1);
      ep_u[pu] = make_int2(((rA & 127) << 17) | cA, (int)((u1 << 16) | u0));
      int pi = atomicAdd(&ci[cA >> 7], 1);
      ep_i[pi] = make_int2(((cA & 127) << 17) | rA, (int)((i1 << 16) | i0));
    }
    // edge i + HALF_NNZ
    {
      uint32_t u0 = f2bfbits(vB * mask_from_bits(mA1));
      uint32_t u1 = f2bfbits(vB * mask_from_bits(mB1));
      uint32_t i0 = f2bfbits(vB * mask_from_bits(mC1));
      uint32_t i1 = f2bfbits(vB * mask_from_bits(mD1));
      int pu = atomicAdd(&cu[rB >> 7], 1);
      ep_u[pu] = make_int2(((rB & 127) << 17) | cB, (int)((u1 << 16) | u0));
      int pi = atomicAdd(&ci[cB >> 7], 1);
      ep_i[pi] = make_int2(((cB & 127) << 17) | rB, (int)((i1 << 16) | i0));
    }
  }
}

// ---------------- merged per-bucket counting sort (LDS edge buffer) -----------
__global__ __launch_bounds__(256) void k_csort2(const int2* __restrict__ epu_raw,
                                                const int* __restrict__ cnt2d_u,
                                                int2* __restrict__ ep_u,
                                                int* __restrict__ row_ptr,
                                                const int2* __restrict__ epi_raw,
                                                const int* __restrict__ cnt2d_i,
                                                int2* __restrict__ ep_i,
                                                int* __restrict__ col_ptr) {
  const int2* ep_raw; const int* cnt2d; int2* ep_srt; int* rp; int nrows, nbkt, b;
  if (blockIdx.x < NBKT_U) {
    b = blockIdx.x; ep_raw = epu_raw; cnt2d = cnt2d_u; ep_srt = ep_u;
    rp = row_ptr; nrows = N_USERS; nbkt = NBKT_U;
  } else {
    b = blockIdx.x - NBKT_U; ep_raw = epi_raw; cnt2d = cnt2d_i; ep_srt = ep_i;
    rp = col_ptr; nrows = N_ITEMS; nbkt = NBKT_I;
  }
  int beg = cnt2d[b * NBLK];
  int end = (b + 1 < nbkt) ? cnt2d[(b + 1) * NBLK] : NNZ;
  __shared__ int2 ebuf[CSCAP];
  __shared__ int cnt[RB];
  __shared__ int loff[RB];
  __shared__ int lcur[RB];
  for (int i = threadIdx.x; i < RB; i += 256) cnt[i] = 0;
  __syncthreads();
  for (int k = beg + threadIdx.x; k < end; k += 256) {
    int2 p = ep_raw[k];
    int li = k - beg;
    if (li < CSCAP) ebuf[li] = p;
    atomicAdd(&cnt[(p.x >> 17) & 127], 1);
  }
  __syncthreads();
  if (threadIdx.x < 64) {
    int l = threadIdx.x;
    int e0 = cnt[2 * l], e1 = cnt[2 * l + 1];
    int s = e0 + e1;
    int incl = s;
    for (int off = 1; off < 64; off <<= 1) {
      int t = __shfl_up(incl, off);
      if (l >= off) incl += t;
    }
    int excl = incl - s;
    loff[2 * l] = excl;
    loff[2 * l + 1] = excl + e0;
  }
  __syncthreads();
  for (int r = threadIdx.x; r < RB; r += 256) {
    lcur[r] = beg + loff[r];
    int row = b * RB + r;
    if (row < nrows) rp[row] = beg + loff[r];
  }
  if (b == 0 && threadIdx.x == 0) rp[nrows] = NNZ;
  __syncthreads();
  for (int k = beg + threadIdx.x; k < end; k += 256) {
    int li = k - beg;
    int2 p = (li < CSCAP) ? ebuf[li] : ep_raw[k];
    int pos = atomicAdd(&lcur[(p.x >> 17) & 127], 1);
    ep_srt[pos] = p;
  }
}

// ---------------- merged f32 -> bf16 convert ----------------
__global__ __launch_bounds__(256) void k_tobf2(const float4* __restrict__ Eu,
                                               const float4* __restrict__ Ei,
                                               ushort4* __restrict__ ou,
                                               ushort4* __restrict__ oi) {
  int i = blockIdx.x * 256 + threadIdx.x;
  const int nu4 = N_USERS * DIM / 4;
  float4 v; ushort4* o;
  if (i < nu4) { v = Eu[i]; o = ou + i; }
  else { v = Ei[i - nu4]; o = oi + (i - nu4); }
  ushort4 r;
  r.x = (unsigned short)f2bfbits(v.x);
  r.y = (unsigned short)f2bfbits(v.y);
  r.z = (unsigned short)f2bfbits(v.z);
  r.w = (unsigned short)f2bfbits(v.w);
  *o = r;
}

// ---------------- merged SpMM: 16-deep branchless pipelined gathers ----------
// blocks [0,UBLK): user rows; rest: item rows
// LAYER 0: out = bf16(dropA @ X).  LAYER 1: out = bf16(E0 + Z1 + dropA @ X)
template<int LAYER>
__global__ __launch_bounds__(256) void k_spmm2(const int* __restrict__ row_ptr,
                                               const int2* __restrict__ ep_u,
                                               const bf16* __restrict__ Xu,
                                               const float* __restrict__ Eu0,
                                               const bf16* __restrict__ Zu1,
                                               bf16* __restrict__ outU,
                                               const int* __restrict__ col_ptr,
                                               const int2* __restrict__ ep_i,
                                               const bf16* __restrict__ Xi,
                                               const float* __restrict__ Ei0,
                                               const bf16* __restrict__ Zi1,
                                               bf16* __restrict__ outI) {
  const int* ptr; const int2* ep; const bf16* X; const float* E0; const bf16* Z1; bf16* o;
  int wbase;
  if (blockIdx.x < UBLK) {
    ptr = row_ptr; ep = ep_u; X = Xu; E0 = Eu0; Z1 = Zu1; o = outU;
    wbase = blockIdx.x * 4;
  } else {
    ptr = col_ptr; ep = ep_i; X = Xi; E0 = Ei0; Z1 = Zi1; o = outI;
    wbase = (blockIdx.x - UBLK) * 4;
  }
  int lane = threadIdx.x & 63;
  int w = __builtin_amdgcn_readfirstlane(wbase + (threadIdx.x >> 6));
  int beg = ptr[w], end = ptr[w + 1];          // uniform -> s_load
  float acc = 0.f;
  for (int k = beg; k < end; k += 16) {
    int nn = min(16, end - k);
    float xv[16], vv[16];
#pragma unroll
    for (int j = 0; j < 16; ++j) {
      if (j < nn) {
        int2 p = ep[k + j];                     // uniform -> wide s_load
        uint32_t y = (uint32_t)p.y;
        uint32_t vb = LAYER ? (y & 0xFFFF0000u) : (y << 16);
        vv[j] = __uint_as_float(vb);
        xv[j] = __bfloat162float(X[(size_t)(p.x & 0x1FFFF) * DIM + lane]);
      } else { vv[j] = 0.f; xv[j] = 0.f; }
    }
#pragma unroll
    for (int j = 0; j < 16; ++j) acc += vv[j] * xv[j];
  }
  size_t off = (size_t)w * DIM + lane;
  if (LAYER == 0) {
    o[off] = __float2bfloat16(acc);
  } else {
    float s = E0[off] + __bfloat162float(Z1[off]) + acc;
    o[off] = __float2bfloat16(s);
  }
}

// ---------------- merged W reductions ----------------
__global__ __launch_bounds__(256) void k_wred2(const bf16* __restrict__ Xi_tab,
                                               const float* __restrict__ vt,
                                               float* __restrict__ Wu,
                                               const bf16* __restrict__ Xu_tab,
                                               const float* __restrict__ ut,
                                               float* __restrict__ Wi) {
  const bf16* X; const float* Vt; float* W; int n, b;
  if (blockIdx.x < 256) { X = Xi_tab; Vt = vt; W = Wu; n = N_ITEMS; b = blockIdx.x; }
  else { X = Xu_tab; Vt = ut; W = Wi; n = N_USERS; b = blockIdx.x - 256; }
  int lane = threadIdx.x & 63;
  int w = b * 4 + (threadIdx.x >> 6);
  const int nw = 1024;
  float acc[QDIM] = {0.f, 0.f, 0.f, 0.f, 0.f};
  for (int i = w; i < n; i += nw) {
    float x = __bfloat162float(X[(size_t)i * DIM + lane]);
#pragma unroll
    for (int q = 0; q < QDIM; ++q) acc[q] += Vt[(size_t)q * n + i] * x;
  }
#pragma unroll
  for (int q = 0; q < QDIM; ++q) atomicAdd(&W[q * DIM + lane], acc[q]);
}

// ---------------- batch-row prep + fused dot products ----------------
__global__ __launch_bounds__(256) void k_prep_dots(const int* __restrict__ uids,
                                                   const int* __restrict__ pos,
                                                   const int* __restrict__ neg,
                                                   const float* __restrict__ Eu0,
                                                   const float* __restrict__ Ei0,
                                                   const float* __restrict__ umuls,
                                                   const float* __restrict__ vmuls,
                                                   const bf16* __restrict__ sEubf,
                                                   const bf16* __restrict__ sEibf,
                                                   const float* __restrict__ Wu,
                                                   const float* __restrict__ Wi,
                                                   bf16* __restrict__ Gbf,
                                                   float* __restrict__ scal) {
  int row = (blockIdx.x * 256 + threadIdx.x) >> 6;
  int lane = threadIdx.x & 63;
  if (row >= 3 * BATCH) return;
  if (row < BATCH) {
    int u = uids[row];
    size_t base = (size_t)u * DIM + lane;
    float g = Eu0[base];
#pragma unroll
    for (int q = 0; q < QDIM; ++q) g += umuls[u * QDIM + q] * Wu[q * DIM + lane];
    Gbf[row * DIM + lane] = __float2bfloat16(g);
    float se = __bfloat162float(sEubf[base]);
    float sp = __bfloat162float(sEibf[(size_t)pos[row] * DIM + lane]);
    float sn = __bfloat162float(sEibf[(size_t)neg[row] * DIM + lane]);
    float d = g * se, dp = se * sp, dn = se * sn;
    for (int off = 32; off; off >>= 1) {
      d += __shfl_down(d, off);
      dp += __shfl_down(dp, off);
      dn += __shfl_down(dn, off);
    }
    if (lane == 0) {
      float posu = fminf(fmaxf(d * 5.0f, -5.f), 5.f);
      float diff = dp - dn;
      float bpr = fmaxf(-diff, 0.f) + log1pf(expf(-fabsf(diff)));
      atomicAdd(&scal[SC_POSU], posu);
      atomicAdd(&scal[SC_BPR], bpr);
    }
  } else {
    int r = row - BATCH;
    int it = (r < BATCH) ? pos[r] : neg[r - BATCH];
    size_t base = (size_t)it * DIM + lane;
    float g = Ei0[base];
#pragma unroll
    for (int q = 0; q < QDIM; ++q) g += vmuls[it * QDIM + q] * Wi[q * DIM + lane];
    Gbf[row * DIM + lane] = __float2bfloat16(g);
    float se = __bfloat162float(sEibf[base]);
    float d = g * se;
    for (int off = 32; off; off >>= 1) d += __shfl_down(d, off);
    if (lane == 0)
      atomicAdd(&scal[SC_POSI], fminf(fmaxf(d * 5.0f, -5.f), 5.f));
  }
}

// ---------------- merged InfoNCE denominator (users + items) ----------------
__global__ __launch_bounds__(256) void k_negsum2(const bf16* __restrict__ Gbf,
                                                 const bf16* __restrict__ sEubf,
                                                 float* __restrict__ Su,
                                                 const bf16* __restrict__ sEibf,
                                                 float* __restrict__ Si) {
  const bf16* G; const bf16* SE; float* S; int n, n_bblk, uch, bid;
  if (blockIdx.x < 512) {
    G = Gbf; SE = sEubf; S = Su; n = N_USERS; n_bblk = 4; uch = 128; bid = blockIdx.x;
  } else {
    G = Gbf + (size_t)BATCH * DIM; SE = sEibf; S = Si; n = N_ITEMS;
    n_bblk = 8; uch = 64; bid = blockIdx.x - 512;
  }
  int bblk = bid % n_bblk;
  int uc = bid / n_bblk;
  int wid = threadIdx.x >> 6;
  int lane = threadIdx.x & 63;
  int b0 = bblk * 256 + wid * 64;
  int fr = lane & 15, fq = lane >> 4;

  bf16x8 a0[4], a1[4];
#pragma unroll
  for (int t = 0; t < 4; ++t) {
    a0[t] = *(const bf16x8*)(G + (size_t)(b0 + t * 16 + fr) * DIM + fq * 8);
    a1[t] = *(const bf16x8*)(G + (size_t)(b0 + t * 16 + fr) * DIM + 32 + fq * 8);
  }

  int tiles = n / 16;
  int per = ((tiles + uch - 1) / uch) * 16;
  int u_lo = uc * per;
  int u_hi = min(n, u_lo + per);

  float racc[16];
#pragma unroll
  for (int j = 0; j < 16; ++j) racc[j] = 0.f;
  const float invT = 5.0f;
  for (int u0 = u_lo; u0 < u_hi; u0 += 16) {
    bf16x8 bfr0 = *(const bf16x8*)(SE + (size_t)(u0 + fr) * DIM + fq * 8);
    bf16x8 bfr1 = *(const bf16x8*)(SE + (size_t)(u0 + fr) * DIM + 32 + fq * 8);
#pragma unroll
    for (int t = 0; t < 4; ++t) {
      f32x4 c = {0.f, 0.f, 0.f, 0.f};
      c = __builtin_amdgcn_mfma_f32_16x16x32_bf16(a0[t], bfr0, c, 0, 0, 0);
      c = __builtin_amdgcn_mfma_f32_16x16x32_bf16(a1[t], bfr1, c, 0, 0, 0);
#pragma unroll
      for (int j = 0; j < 4; ++j) racc[t * 4 + j] += __expf(c[j] * invT);
    }
  }
#pragma unroll
  for (int t = 0; t < 4; ++t) {
#pragma unroll
    for (int j = 0; j < 4; ++j) {
      float v = racc[t * 4 + j];
      v += __shfl_xor(v, 1);
      v += __shfl_xor(v, 2);
      v += __shfl_xor(v, 4);
      v += __shfl_xor(v, 8);
      if (fr == 0) atomicAdd(&S[b0 + t * 16 + fq * 4 + j], v);
    }
  }
}

// ---------------- parallel log-sum of Su/Si ----------------
__global__ __launch_bounds__(256) void k_logsum(const float* __restrict__ Su,
                                                const float* __restrict__ Si,
                                                float* __restrict__ scal) {
  int i = blockIdx.x * 256 + threadIdx.x;
  float lu = 0.f, li = 0.f;
  if (i < BATCH) lu = logf(Su[i] + 1e-8f);
  else if (i < 3 * BATCH) li = logf(Si[i - BATCH] + 1e-8f);
  for (int off = 32; off; off >>= 1) {
    lu += __shfl_down(lu, off);
    li += __shfl_down(li, off);
  }
  __shared__ float pu[4], pi_[4];
  if ((threadIdx.x & 63) == 0) { pu[threadIdx.x >> 6] = lu; pi_[threadIdx.x >> 6] = li; }
  __syncthreads();
  if (threadIdx.x == 0) {
    atomicAdd(&scal[SC_NLU], pu[0] + pu[1] + pu[2] + pu[3]);
    atomicAdd(&scal[SC_NLI], pi_[0] + pi_[1] + pi_[2] + pi_[3]);
  }
}

// ---------------- merged sum of squares (float4) ----------------
__global__ __launch_bounds__(256) void k_sumsq2(const float4* __restrict__ A, int na4,
                                                const float4* __restrict__ B, int nb4,
                                                float* __restrict__ out) {
  int i = blockIdx.x * 256 + threadIdx.x;
  int stride = gridDim.x * 256;
  float s = 0.f;
  for (; i < na4 + nb4; i += stride) {
    float4 v = (i < na4) ? A[i] : B[i - na4];
    s += v.x * v.x + v.y * v.y + v.z * v.z + v.w * v.w;
  }
  for (int off = 32; off; off >>= 1) s += __shfl_down(s, off);
  __shared__ float part[4];
  if ((threadIdx.x & 63) == 0) part[threadIdx.x >> 6] = s;
  __syncthreads();
  if (threadIdx.x == 0) atomicAdd(out, part[0] + part[1] + part[2] + part[3]);
}

// ---------------- final combine (1 thread) ----------------
__global__ void k_finish(const float* __restrict__ scal, float* __restrict__ out) {
  float neg_score = scal[SC_NLU] / (float)BATCH + scal[SC_NLI] / (float)(2 * BATCH);
  float pos_score = scal[SC_POSU] / (float)BATCH + scal[SC_POSI] / (float)(2 * BATCH);
  float loss_s = -pos_score + neg_score;
  float loss_r = scal[SC_BPR] / (float)BATCH;
  float ls = 0.2f * loss_s;
  float reg = 1e-5f * scal[SC_SUMSQ];
  out[0] = loss_r + ls + reg;
  out[1] = loss_r;
  out[2] = ls;
}

extern "C" void kernel_launch(void* const* d_in, const int* in_sizes, int n_in,
                              void* d_out, int out_size, void* d_ws, size_t ws_size,
                              hipStream_t stream) {
  const float* Eu0   = (const float*)d_in[0];
  const float* Ei0   = (const float*)d_in[1];
  const float* umuls = (const float*)d_in[2];
  const float* vmuls = (const float*)d_in[3];
  const float* ut    = (const float*)d_in[4];
  const float* vt    = (const float*)d_in[5];
  const float* adj_vals = (const float*)d_in[6];
  const int* adj_rows = (const int*)d_in[7];
  const int* adj_cols = (const int*)d_in[8];
  const int* uids = (const int*)d_in[9];
  const int* pos  = (const int*)d_in[10];
  const int* neg  = (const int*)d_in[11];
  float* out = (float*)d_out;

  char* w = (char*)d_ws;
  size_t off = 0;
  auto alloc = [&](size_t bytes) -> void* {
    void* p = w + off;
    off = (off + bytes + 255) & ~(size_t)255;
    return p;
  };
  int2* epu_raw = (int2*)alloc(sizeof(int2) * NNZ);
  int2* epi_raw = (int2*)alloc(sizeof(int2) * NNZ);
  int2* ep_u = (int2*)alloc(sizeof(int2) * NNZ);
  int2* ep_i = (int2*)alloc(sizeof(int2) * NNZ);
  int* cnt2d_u = (int*)alloc(sizeof(int) * N2D_U);
  int* cnt2d_i = (int*)alloc(sizeof(int) * N2D_I);
  int* row_ptr = (int*)alloc(sizeof(int) * (N_USERS + 1));
  int* col_ptr = (int*)alloc(sizeof(int) * (N_ITEMS + 1));
  bf16* Eu0bf = (bf16*)alloc(sizeof(bf16) * N_USERS * DIM);
  bf16* Ei0bf = (bf16*)alloc(sizeof(bf16) * N_ITEMS * DIM);
  bf16* Zu1bf = (bf16*)alloc(sizeof(bf16) * N_USERS * DIM);
  bf16* Zi1bf = (bf16*)alloc(sizeof(bf16) * N_ITEMS * DIM);
  bf16* sEubf = (bf16*)alloc(sizeof(bf16) * N_USERS * DIM);
  bf16* sEibf = (bf16*)alloc(sizeof(bf16) * N_ITEMS * DIM);
  int* bsum_u = (int*)alloc(sizeof(int) * 64);
  int* boff_u = (int*)alloc(sizeof(int) * 64);
  int* bsum_i = (int*)alloc(sizeof(int) * 64);
  int* boff_i = (int*)alloc(sizeof(int) * 64);
  // zero-init region: Wu, Wi, Su, Si, scal (contiguous; one memset)
  char* zbase = (char*)(w + off);
  float* Wu = (float*)alloc(sizeof(float) * QDIM * DIM);
  float* Wi = (float*)alloc(sizeof(float) * QDIM * DIM);
  float* Su = (float*)alloc(sizeof(float) * BATCH);
  float* Si = (float*)alloc(sizeof(float) * 2 * BATCH);
  float* scal = (float*)alloc(sizeof(float) * 8);
  size_t zlen = (size_t)((char*)(w + off) - zbase);
  bf16* Gbf = (bf16*)alloc(sizeof(bf16) * 3 * BATCH * DIM);

  // folded dropout keys: fold_in(key(42), idx) for idx = 0..3
  uint32_t mk[4][2];
  for (uint32_t i = 0; i < 4; ++i) tf2x32(0u, 42u, 0u, i, mk[i][0], mk[i][1]);

  hipMemsetAsync(zbase, 0, zlen, stream);

  // build: bucket counts -> scans -> partition -> per-bucket sort
  k_bcount<<<NBLK, 256, 0, stream>>>(adj_rows, adj_cols, cnt2d_u, cnt2d_i);
  k_tobf2<<<(N_USERS + N_ITEMS) * DIM / 4 / 256, 256, 0, stream>>>(
      (const float4*)Eu0, (const float4*)Ei0, (ushort4*)Eu0bf, (ushort4*)Ei0bf);
  k_bsum2<<<NBU + NBI, 256, 0, stream>>>(cnt2d_u, cnt2d_i, bsum_u, bsum_i);
  k_bscan2<<<2, 64, 0, stream>>>(bsum_u, bsum_i, boff_u, boff_i);
  k_scan32<<<NBU + NBI, 256, 0, stream>>>(cnt2d_u, cnt2d_i, boff_u, boff_i);
  k_part<<<NBLK, 256, 0, stream>>>(adj_rows, adj_cols, adj_vals, cnt2d_u, cnt2d_i,
                                   epu_raw, epi_raw,
                                   mk[0][0], mk[0][1], mk[2][0], mk[2][1],
                                   mk[1][0], mk[1][1], mk[3][0], mk[3][1]);
  k_csort2<<<NBKT_U + NBKT_I, 256, 0, stream>>>(epu_raw, cnt2d_u, ep_u, row_ptr,
                                                epi_raw, cnt2d_i, ep_i, col_ptr);

  // layer 0: Zu1 = dropA @ Ei0, Zi1 = dropA^T @ Eu0 (merged)
  k_spmm2<0><<<(N_USERS + N_ITEMS) * 64 / 256, 256, 0, stream>>>(
      row_ptr, ep_u, Ei0bf, nullptr, nullptr, Zu1bf,
      col_ptr, ep_i, Eu0bf, nullptr, nullptr, Zi1bf);
  k_wred2<<<512, 256, 0, stream>>>(Ei0bf, vt, Wu, Eu0bf, ut, Wi);

  // layer 1: sE = E0 + Z1 + dropA @ Z1(other side) (merged)
  k_spmm2<1><<<(N_USERS + N_ITEMS) * 64 / 256, 256, 0, stream>>>(
      row_ptr, ep_u, Zi1bf, Eu0, Zu1bf, sEubf,
      col_ptr, ep_i, Zu1bf, Ei0, Zi1bf, sEibf);
  k_wred2<<<512, 256, 0, stream>>>(Zi1bf, vt, Wu, Zu1bf, ut, Wi);

  // batch prep + fused pos/BPR dot products
  k_prep_dots<<<(3 * BATCH * 64) / 256, 256, 0, stream>>>(uids, pos, neg, Eu0, Ei0,
                                                          umuls, vmuls, sEubf, sEibf,
                                                          Wu, Wi, Gbf, scal);

  // InfoNCE denominators (merged users+items)
  k_negsum2<<<1024, 256, 0, stream>>>(Gbf, sEubf, Su, sEibf, Si);

  // L2 reg (merged, vectorized)
  k_sumsq2<<<2048, 256, 0, stream>>>((const float4*)Eu0, N_USERS * DIM / 4,
                                     (const float4*)Ei0, N_ITEMS * DIM / 4,
                                     scal + SC_SUMSQ);

  // parallel log-sum + final combine
  k_logsum<<<(3 * BATCH + 255) / 256, 256, 0, stream>>>(Su, Si, scal);
  k_finish<<<1, 1, 0, stream>>>(scal, out);
}

// Round 10
// 506.155 us; speedup vs baseline: 1.2406x; 1.2406x over previous
//
#include <hip/hip_runtime.h>
#include <hip/hip_bf16.h>
#include <stdint.h>

#define N_USERS 100000
#define N_ITEMS 50000
#define DIM     64
#define QDIM    5
#define NNZ     1000000
#define BATCH   1024
#define HALF_NNZ (NNZ/2)

#define RB      128                       // rows per bucket
#define NBKT_U  ((N_USERS + RB - 1) / RB) // 782
#define NBKT_I  ((N_ITEMS + RB - 1) / RB) // 391
#define NBLK    256                       // partition blocks
#define EPB2    ((HALF_NNZ + NBLK - 1) / NBLK) // 1954 edge-PAIRS per block
#define SC_E    4096                      // elements per scan block (256 thr x 16)
#define N2D_U   (NBKT_U * NBLK)           // 200192
#define N2D_I   (NBKT_I * NBLK)           // 100096
#define NBU     ((N2D_U + SC_E - 1) / SC_E) // 49
#define NBI     ((N2D_I + SC_E - 1) / SC_E) // 25
#define UBLK    (N_USERS * 64 / 256)      // 25000 user spmm blocks
#define CSCAP   3072                      // csort LDS edge capacity (24 KB)

typedef __hip_bfloat16 bf16;
typedef __attribute__((ext_vector_type(8))) short bf16x8;
typedef __attribute__((ext_vector_type(4))) float f32x4;

// scalar accumulator slots: [0]=sumsq [1]=posu [2]=posi [3]=bpr [4]=nlu [5]=nli
#define SC_SUMSQ 0
#define SC_POSU  1
#define SC_POSI  2
#define SC_BPR   3
#define SC_NLU   4
#define SC_NLI   5

// ---------------- threefry2x32 (exact JAX block) ----------------
__host__ __device__ inline void tf2x32(uint32_t k0, uint32_t k1,
                                       uint32_t x0, uint32_t x1,
                                       uint32_t& o0, uint32_t& o1) {
  uint32_t ks2 = k0 ^ k1 ^ 0x1BD11BDAu;
  x0 += k0; x1 += k1;
#define TF_R(r) { x0 += x1; x1 = (x1 << (r)) | (x1 >> (32 - (r))); x1 ^= x0; }
  TF_R(13) TF_R(15) TF_R(26) TF_R(6)
  x0 += k1; x1 += ks2 + 1u;
  TF_R(17) TF_R(29) TF_R(16) TF_R(24)
  x0 += ks2; x1 += k0 + 2u;
  TF_R(13) TF_R(15) TF_R(26) TF_R(6)
  x0 += k0; x1 += k1 + 3u;
  TF_R(17) TF_R(29) TF_R(16) TF_R(24)
  x0 += k1; x1 += ks2 + 4u;
  TF_R(13) TF_R(15) TF_R(26) TF_R(6)
  x0 += ks2; x1 += k0 + 5u;
#undef TF_R
  o0 = x0; o1 = x1;
}

__device__ __forceinline__ float mask_from_bits(uint32_t bits) {
  float f = __uint_as_float((bits >> 9) | 0x3f800000u) - 1.0f;
  return (f < 0.75f) ? (1.0f / 0.75f) : 0.0f;
}

__device__ __forceinline__ uint32_t f2bfbits(float f) {
  bf16 h = __float2bfloat16(f);
  return (uint32_t)(*reinterpret_cast<unsigned short*>(&h));
}

// ---------------- bucket counting (edge pairs, matches k_part) ----------------
__global__ __launch_bounds__(256) void k_bcount(const int* __restrict__ rows,
                                                const int* __restrict__ cols,
                                                int* __restrict__ cnt_u,
                                                int* __restrict__ cnt_i) {
  __shared__ int hu[NBKT_U];
  __shared__ int hv[NBKT_I];
  for (int i = threadIdx.x; i < NBKT_U; i += 256) hu[i] = 0;
  for (int i = threadIdx.x; i < NBKT_I; i += 256) hv[i] = 0;
  __syncthreads();
  int beg = blockIdx.x * EPB2, end = min(beg + EPB2, HALF_NNZ);
  for (int i = beg + threadIdx.x; i < end; i += 256) {
    atomicAdd(&hu[rows[i] >> 7], 1);
    atomicAdd(&hu[rows[i + HALF_NNZ] >> 7], 1);
    atomicAdd(&hv[cols[i] >> 7], 1);
    atomicAdd(&hv[cols[i + HALF_NNZ] >> 7], 1);
  }
  __syncthreads();
  for (int i = threadIdx.x; i < NBKT_U; i += 256) cnt_u[i * NBLK + blockIdx.x] = hu[i];
  for (int i = threadIdx.x; i < NBKT_I; i += 256) cnt_i[i * NBLK + blockIdx.x] = hv[i];
}

// ---------------- merged hierarchical scan (user + item) ----------------
__global__ __launch_bounds__(256) void k_bsum2(const int* __restrict__ cnt_u,
                                               const int* __restrict__ cnt_i,
                                               int* __restrict__ bsum_u,
                                               int* __restrict__ bsum_i) {
  const int* cnt; int n, b; int* bsum;
  if (blockIdx.x < NBU) { cnt = cnt_u; n = N2D_U; b = blockIdx.x; bsum = bsum_u; }
  else { cnt = cnt_i; n = N2D_I; b = blockIdx.x - NBU; bsum = bsum_i; }
  int base = b * SC_E + threadIdx.x * 16;
  int s = 0;
#pragma unroll
  for (int j = 0; j < 16; ++j) { int i = base + j; if (i < n) s += cnt[i]; }
  for (int off = 32; off; off >>= 1) s += __shfl_down(s, off);
  __shared__ int ws[4];
  if ((threadIdx.x & 63) == 0) ws[threadIdx.x >> 6] = s;
  __syncthreads();
  if (threadIdx.x == 0) bsum[b] = ws[0] + ws[1] + ws[2] + ws[3];
}

__global__ __launch_bounds__(64) void k_bscan2(const int* __restrict__ bsum_u,
                                               const int* __restrict__ bsum_i,
                                               int* __restrict__ boff_u,
                                               int* __restrict__ boff_i) {
  const int* bsum; int nb; int* boff;
  if (blockIdx.x == 0) { bsum = bsum_u; nb = NBU; boff = boff_u; }
  else { bsum = bsum_i; nb = NBI; boff = boff_i; }
  int lane = threadIdx.x;
  int v = (lane < nb) ? bsum[lane] : 0;
  int incl = v;
  for (int off = 1; off < 64; off <<= 1) {
    int t = __shfl_up(incl, off);
    if (lane >= off) incl += t;
  }
  if (lane < nb) boff[lane] = incl - v;
}

// in-place exclusive scan (ptr aliases cnt; per-thread chunks disjoint)
__global__ __launch_bounds__(256) void k_scan32(int* __restrict__ cnt_u,
                                                int* __restrict__ cnt_i,
                                                const int* __restrict__ boff_u,
                                                const int* __restrict__ boff_i) {
  int* cnt; int n, b; const int* boff;
  if (blockIdx.x < NBU) { cnt = cnt_u; n = N2D_U; b = blockIdx.x; boff = boff_u; }
  else { cnt = cnt_i; n = N2D_I; b = blockIdx.x - NBU; boff = boff_i; }
  int base = b * SC_E + threadIdx.x * 16;
  int c[16]; int s = 0;
#pragma unroll
  for (int j = 0; j < 16; ++j) { int i = base + j; c[j] = (i < n) ? cnt[i] : 0; s += c[j]; }
  int lane = threadIdx.x & 63, wid = threadIdx.x >> 6;
  int incl = s;
  for (int off = 1; off < 64; off <<= 1) {
    int t = __shfl_up(incl, off);
    if (lane >= off) incl += t;
  }
  __shared__ int wsum[4];
  if (lane == 63) wsum[wid] = incl;
  __syncthreads();
  int wpre = 0;
  for (int k = 0; k < wid; ++k) wpre += wsum[k];
  int run = boff[b] + wpre + (incl - s);
#pragma unroll
  for (int j = 0; j < 16; ++j) {
    int i = base + j;
    if (i < n) { cnt[i] = run; run += c[j]; }
  }
}

// ---------------- partition (edge pairs: both threefry outputs used) ----------
// payload int2: x = (local_row<<17)|col17, y = (bf16(v_layer1)<<16)|bf16(v_layer0)
__global__ __launch_bounds__(256) void k_part(const int* __restrict__ rows,
                                              const int* __restrict__ cols,
                                              const float* __restrict__ adj_vals,
                                              const int* __restrict__ off_u,
                                              const int* __restrict__ off_i,
                                              int2* __restrict__ ep_u,
                                              int2* __restrict__ ep_i,
                                              uint32_t a0, uint32_t a1,
                                              uint32_t b0, uint32_t b1,
                                              uint32_t c0, uint32_t c1,
                                              uint32_t d0, uint32_t d1) {
  __shared__ int cu[NBKT_U];
  __shared__ int ci[NBKT_I];
  for (int i = threadIdx.x; i < NBKT_U; i += 256) cu[i] = off_u[i * NBLK + blockIdx.x];
  for (int i = threadIdx.x; i < NBKT_I; i += 256) ci[i] = off_i[i * NBLK + blockIdx.x];
  __syncthreads();
  int beg = blockIdx.x * EPB2, end = min(beg + EPB2, HALF_NNZ);
  for (int i = beg + threadIdx.x; i < end; i += 256) {
    int e2 = i + HALF_NNZ;
    int rA = rows[i], cA = cols[i];
    int rB = rows[e2], cB = cols[e2];
    float vA = adj_vals[i], vB = adj_vals[e2];
    uint32_t mA0, mA1, mB0, mB1, mC0, mC1, mD0, mD1;
    tf2x32(a0, a1, (uint32_t)i, (uint32_t)e2, mA0, mA1);  // user L0
    tf2x32(b0, b1, (uint32_t)i, (uint32_t)e2, mB0, mB1);  // user L1
    tf2x32(c0, c1, (uint32_t)i, (uint32_t)e2, mC0, mC1);  // item L0
    tf2x32(d0, d1, (uint32_t)i, (uint32_t)e2, mD0, mD1);  // item L1
    // edge i
    {
      uint32_t u0 = f2bfbits(vA * mask_from_bits(mA0));
      uint32_t u1 = f2bfbits(vA * mask_from_bits(mB0));
      uint32_t i0 = f2bfbits(vA * mask_from_bits(mC0));
      uint32_t i1 = f2bfbits(vA * mask_from_bits(mD0));
      int pu = atomicAdd(&cu[rA >> 7], 1);
      ep_u[pu] = make_int2(((rA & 127) << 17) | cA, (int)((u1 << 16) | u0));
      int pi = atomicAdd(&ci[cA >> 7], 1);
      ep_i[pi] = make_int2(((cA & 127) << 17) | rA, (int)((i1 << 16) | i0));
    }
    // edge i + HALF_NNZ
    {
      uint32_t u0 = f2bfbits(vB * mask_from_bits(mA1));
      uint32_t u1 = f2bfbits(vB * mask_from_bits(mB1));
      uint32_t i0 = f2bfbits(vB * mask_from_bits(mC1));
      uint32_t i1 = f2bfbits(vB * mask_from_bits(mD1));
      int pu = atomicAdd(&cu[rB >> 7], 1);
      ep_u[pu] = make_int2(((rB & 127) << 17) | cB, (int)((u1 << 16) | u0));
      int pi = atomicAdd(&ci[cB >> 7], 1);
      ep_i[pi] = make_int2(((cB & 127) << 17) | rB, (int)((i1 << 16) | i0));
    }
  }
}

// ---------------- merged per-bucket counting sort (LDS edge buffer) -----------
__global__ __launch_bounds__(256) void k_csort2(const int2* __restrict__ epu_raw,
                                                const int* __restrict__ cnt2d_u,
                                                int2* __restrict__ ep_u,
                                                int* __restrict__ row_ptr,
                                                const int2* __restrict__ epi_raw,
                                                const int* __restrict__ cnt2d_i,
                                                int2* __restrict__ ep_i,
                                                int* __restrict__ col_ptr) {
  const int2* ep_raw; const int* cnt2d; int2* ep_srt; int* rp; int nrows, nbkt, b;
  if (blockIdx.x < NBKT_U) {
    b = blockIdx.x; ep_raw = epu_raw; cnt2d = cnt2d_u; ep_srt = ep_u;
    rp = row_ptr; nrows = N_USERS; nbkt = NBKT_U;
  } else {
    b = blockIdx.x - NBKT_U; ep_raw = epi_raw; cnt2d = cnt2d_i; ep_srt = ep_i;
    rp = col_ptr; nrows = N_ITEMS; nbkt = NBKT_I;
  }
  int beg = cnt2d[b * NBLK];
  int end = (b + 1 < nbkt) ? cnt2d[(b + 1) * NBLK] : NNZ;
  __shared__ int2 ebuf[CSCAP];
  __shared__ int cnt[RB];
  __shared__ int loff[RB];
  __shared__ int lcur[RB];
  for (int i = threadIdx.x; i < RB; i += 256) cnt[i] = 0;
  __syncthreads();
  for (int k = beg + threadIdx.x; k < end; k += 256) {
    int2 p = ep_raw[k];
    int li = k - beg;
    if (li < CSCAP) ebuf[li] = p;
    atomicAdd(&cnt[(p.x >> 17) & 127], 1);
  }
  __syncthreads();
  if (threadIdx.x < 64) {
    int l = threadIdx.x;
    int e0 = cnt[2 * l], e1 = cnt[2 * l + 1];
    int s = e0 + e1;
    int incl = s;
    for (int off = 1; off < 64; off <<= 1) {
      int t = __shfl_up(incl, off);
      if (l >= off) incl += t;
    }
    int excl = incl - s;
    loff[2 * l] = excl;
    loff[2 * l + 1] = excl + e0;
  }
  __syncthreads();
  for (int r = threadIdx.x; r < RB; r += 256) {
    lcur[r] = beg + loff[r];
    int row = b * RB + r;
    if (row < nrows) rp[row] = beg + loff[r];
  }
  if (b == 0 && threadIdx.x == 0) rp[nrows] = NNZ;
  __syncthreads();
  for (int k = beg + threadIdx.x; k < end; k += 256) {
    int li = k - beg;
    int2 p = (li < CSCAP) ? ebuf[li] : ep_raw[k];
    int pos = atomicAdd(&lcur[(p.x >> 17) & 127], 1);
    ep_srt[pos] = p;
  }
}

// ---------------- merged f32 -> bf16 convert ----------------
__global__ __launch_bounds__(256) void k_tobf2(const float4* __restrict__ Eu,
                                               const float4* __restrict__ Ei,
                                               ushort4* __restrict__ ou,
                                               ushort4* __restrict__ oi) {
  int i = blockIdx.x * 256 + threadIdx.x;
  const int nu4 = N_USERS * DIM / 4;
  float4 v; ushort4* o;
  if (i < nu4) { v = Eu[i]; o = ou + i; }
  else { v = Ei[i - nu4]; o = oi + (i - nu4); }
  ushort4 r;
  r.x = (unsigned short)f2bfbits(v.x);
  r.y = (unsigned short)f2bfbits(v.y);
  r.z = (unsigned short)f2bfbits(v.z);
  r.w = (unsigned short)f2bfbits(v.w);
  *o = r;
}

// ---------------- merged SpMM: 8-deep NAMED-REGISTER pipelined gathers -------
// blocks [0,UBLK): user rows; rest: item rows
// LAYER 0: out = bf16(dropA @ X).  LAYER 1: out = bf16(E0 + Z1 + dropA @ X)
template<int LAYER>
__global__ __launch_bounds__(256) void k_spmm2(const int* __restrict__ row_ptr,
                                               const int2* __restrict__ ep_u,
                                               const bf16* __restrict__ Xu,
                                               const float* __restrict__ Eu0,
                                               const bf16* __restrict__ Zu1,
                                               bf16* __restrict__ outU,
                                               const int* __restrict__ col_ptr,
                                               const int2* __restrict__ ep_i,
                                               const bf16* __restrict__ Xi,
                                               const float* __restrict__ Ei0,
                                               const bf16* __restrict__ Zi1,
                                               bf16* __restrict__ outI) {
  const int* ptr; const int2* ep; const bf16* X; const float* E0; const bf16* Z1; bf16* o;
  int wbase;
  if (blockIdx.x < UBLK) {
    ptr = row_ptr; ep = ep_u; X = Xu; E0 = Eu0; Z1 = Zu1; o = outU;
    wbase = blockIdx.x * 4;
  } else {
    ptr = col_ptr; ep = ep_i; X = Xi; E0 = Ei0; Z1 = Zi1; o = outI;
    wbase = (blockIdx.x - UBLK) * 4;
  }
  int lane = threadIdx.x & 63;
  int w = __builtin_amdgcn_readfirstlane(wbase + (threadIdx.x >> 6));
  int beg = ptr[w], end = ptr[w + 1];          // uniform -> s_load
  float acc = 0.f;
  int k = beg;
  int kend8 = beg + ((end - beg) & ~7);        // full chunks of 8, branchless body
#define VB_(y) __uint_as_float(LAYER ? ((uint32_t)(y) & 0xFFFF0000u) : ((uint32_t)(y) << 16))
#define XG_(p) __bfloat162float(X[(size_t)((p).x & 0x1FFFF) * DIM + lane])
  for (; k < kend8; k += 8) {
    int2 p0 = ep[k + 0]; int2 p1 = ep[k + 1]; int2 p2 = ep[k + 2]; int2 p3 = ep[k + 3];
    int2 p4 = ep[k + 4]; int2 p5 = ep[k + 5]; int2 p6 = ep[k + 6]; int2 p7 = ep[k + 7];
    float x0 = XG_(p0); float x1 = XG_(p1); float x2 = XG_(p2); float x3 = XG_(p3);
    float x4 = XG_(p4); float x5 = XG_(p5); float x6 = XG_(p6); float x7 = XG_(p7);
    acc += VB_(p0.y) * x0; acc += VB_(p1.y) * x1;
    acc += VB_(p2.y) * x2; acc += VB_(p3.y) * x3;
    acc += VB_(p4.y) * x4; acc += VB_(p5.y) * x5;
    acc += VB_(p6.y) * x6; acc += VB_(p7.y) * x7;
  }
  for (; k < end; ++k) {
    int2 p = ep[k];
    acc += VB_(p.y) * XG_(p);
  }
#undef VB_
#undef XG_
  size_t off = (size_t)w * DIM + lane;
  if (LAYER == 0) {
    o[off] = __float2bfloat16(acc);
  } else {
    float s = E0[off] + __bfloat162float(Z1[off]) + acc;
    o[off] = __float2bfloat16(s);
  }
}

// ---------------- merged W reductions ----------------
__global__ __launch_bounds__(256) void k_wred2(const bf16* __restrict__ Xi_tab,
                                               const float* __restrict__ vt,
                                               float* __restrict__ Wu,
                                               const bf16* __restrict__ Xu_tab,
                                               const float* __restrict__ ut,
                                               float* __restrict__ Wi) {
  const bf16* X; const float* Vt; float* W; int n, b;
  if (blockIdx.x < 256) { X = Xi_tab; Vt = vt; W = Wu; n = N_ITEMS; b = blockIdx.x; }
  else { X = Xu_tab; Vt = ut; W = Wi; n = N_USERS; b = blockIdx.x - 256; }
  int lane = threadIdx.x & 63;
  int w = b * 4 + (threadIdx.x >> 6);
  const int nw = 1024;
  float acc[QDIM] = {0.f, 0.f, 0.f, 0.f, 0.f};
  for (int i = w; i < n; i += nw) {
    float x = __bfloat162float(X[(size_t)i * DIM + lane]);
#pragma unroll
    for (int q = 0; q < QDIM; ++q) acc[q] += Vt[(size_t)q * n + i] * x;
  }
#pragma unroll
  for (int q = 0; q < QDIM; ++q) atomicAdd(&W[q * DIM + lane], acc[q]);
}

// ---------------- batch-row prep + fused dot products ----------------
__global__ __launch_bounds__(256) void k_prep_dots(const int* __restrict__ uids,
                                                   const int* __restrict__ pos,
                                                   const int* __restrict__ neg,
                                                   const float* __restrict__ Eu0,
                                                   const float* __restrict__ Ei0,
                                                   const float* __restrict__ umuls,
                                                   const float* __restrict__ vmuls,
                                                   const bf16* __restrict__ sEubf,
                                                   const bf16* __restrict__ sEibf,
                                                   const float* __restrict__ Wu,
                                                   const float* __restrict__ Wi,
                                                   bf16* __restrict__ Gbf,
                                                   float* __restrict__ scal) {
  int row = (blockIdx.x * 256 + threadIdx.x) >> 6;
  int lane = threadIdx.x & 63;
  if (row >= 3 * BATCH) return;
  if (row < BATCH) {
    int u = uids[row];
    size_t base = (size_t)u * DIM + lane;
    float g = Eu0[base];
#pragma unroll
    for (int q = 0; q < QDIM; ++q) g += umuls[u * QDIM + q] * Wu[q * DIM + lane];
    Gbf[row * DIM + lane] = __float2bfloat16(g);
    float se = __bfloat162float(sEubf[base]);
    float sp = __bfloat162float(sEibf[(size_t)pos[row] * DIM + lane]);
    float sn = __bfloat162float(sEibf[(size_t)neg[row] * DIM + lane]);
    float d = g * se, dp = se * sp, dn = se * sn;
    for (int off = 32; off; off >>= 1) {
      d += __shfl_down(d, off);
      dp += __shfl_down(dp, off);
      dn += __shfl_down(dn, off);
    }
    if (lane == 0) {
      float posu = fminf(fmaxf(d * 5.0f, -5.f), 5.f);
      float diff = dp - dn;
      float bpr = fmaxf(-diff, 0.f) + log1pf(expf(-fabsf(diff)));
      atomicAdd(&scal[SC_POSU], posu);
      atomicAdd(&scal[SC_BPR], bpr);
    }
  } else {
    int r = row - BATCH;
    int it = (r < BATCH) ? pos[r] : neg[r - BATCH];
    size_t base = (size_t)it * DIM + lane;
    float g = Ei0[base];
#pragma unroll
    for (int q = 0; q < QDIM; ++q) g += vmuls[it * QDIM + q] * Wi[q * DIM + lane];
    Gbf[row * DIM + lane] = __float2bfloat16(g);
    float se = __bfloat162float(sEibf[base]);
    float d = g * se;
    for (int off = 32; off; off >>= 1) d += __shfl_down(d, off);
    if (lane == 0)
      atomicAdd(&scal[SC_POSI], fminf(fmaxf(d * 5.0f, -5.f), 5.f));
  }
}

// ---------------- merged InfoNCE denominator (users + items) ----------------
__global__ __launch_bounds__(256) void k_negsum2(const bf16* __restrict__ Gbf,
                                                 const bf16* __restrict__ sEubf,
                                                 float* __restrict__ Su,
                                                 const bf16* __restrict__ sEibf,
                                                 float* __restrict__ Si) {
  const bf16* G; const bf16* SE; float* S; int n, n_bblk, uch, bid;
  if (blockIdx.x < 512) {
    G = Gbf; SE = sEubf; S = Su; n = N_USERS; n_bblk = 4; uch = 128; bid = blockIdx.x;
  } else {
    G = Gbf + (size_t)BATCH * DIM; SE = sEibf; S = Si; n = N_ITEMS;
    n_bblk = 8; uch = 64; bid = blockIdx.x - 512;
  }
  int bblk = bid % n_bblk;
  int uc = bid / n_bblk;
  int wid = threadIdx.x >> 6;
  int lane = threadIdx.x & 63;
  int b0 = bblk * 256 + wid * 64;
  int fr = lane & 15, fq = lane >> 4;

  bf16x8 a0[4], a1[4];
#pragma unroll
  for (int t = 0; t < 4; ++t) {
    a0[t] = *(const bf16x8*)(G + (size_t)(b0 + t * 16 + fr) * DIM + fq * 8);
    a1[t] = *(const bf16x8*)(G + (size_t)(b0 + t * 16 + fr) * DIM + 32 + fq * 8);
  }

  int tiles = n / 16;
  int per = ((tiles + uch - 1) / uch) * 16;
  int u_lo = uc * per;
  int u_hi = min(n, u_lo + per);

  float racc[16];
#pragma unroll
  for (int j = 0; j < 16; ++j) racc[j] = 0.f;
  const float invT = 5.0f;
  for (int u0 = u_lo; u0 < u_hi; u0 += 16) {
    bf16x8 bfr0 = *(const bf16x8*)(SE + (size_t)(u0 + fr) * DIM + fq * 8);
    bf16x8 bfr1 = *(const bf16x8*)(SE + (size_t)(u0 + fr) * DIM + 32 + fq * 8);
#pragma unroll
    for (int t = 0; t < 4; ++t) {
      f32x4 c = {0.f, 0.f, 0.f, 0.f};
      c = __builtin_amdgcn_mfma_f32_16x16x32_bf16(a0[t], bfr0, c, 0, 0, 0);
      c = __builtin_amdgcn_mfma_f32_16x16x32_bf16(a1[t], bfr1, c, 0, 0, 0);
#pragma unroll
      for (int j = 0; j < 4; ++j) racc[t * 4 + j] += __expf(c[j] * invT);
    }
  }
#pragma unroll
  for (int t = 0; t < 4; ++t) {
#pragma unroll
    for (int j = 0; j < 4; ++j) {
      float v = racc[t * 4 + j];
      v += __shfl_xor(v, 1);
      v += __shfl_xor(v, 2);
      v += __shfl_xor(v, 4);
      v += __shfl_xor(v, 8);
      if (fr == 0) atomicAdd(&S[b0 + t * 16 + fq * 4 + j], v);
    }
  }
}

// ---------------- parallel log-sum of Su/Si ----------------
__global__ __launch_bounds__(256) void k_logsum(const float* __restrict__ Su,
                                                const float* __restrict__ Si,
                                                float* __restrict__ scal) {
  int i = blockIdx.x * 256 + threadIdx.x;
  float lu = 0.f, li = 0.f;
  if (i < BATCH) lu = logf(Su[i] + 1e-8f);
  else if (i < 3 * BATCH) li = logf(Si[i - BATCH] + 1e-8f);
  for (int off = 32; off; off >>= 1) {
    lu += __shfl_down(lu, off);
    li += __shfl_down(li, off);
  }
  __shared__ float pu[4], pi_[4];
  if ((threadIdx.x & 63) == 0) { pu[threadIdx.x >> 6] = lu; pi_[threadIdx.x >> 6] = li; }
  __syncthreads();
  if (threadIdx.x == 0) {
    atomicAdd(&scal[SC_NLU], pu[0] + pu[1] + pu[2] + pu[3]);
    atomicAdd(&scal[SC_NLI], pi_[0] + pi_[1] + pi_[2] + pi_[3]);
  }
}

// ---------------- merged sum of squares (float4) ----------------
__global__ __launch_bounds__(256) void k_sumsq2(const float4* __restrict__ A, int na4,
                                                const float4* __restrict__ B, int nb4,
                                                float* __restrict__ out) {
  int i = blockIdx.x * 256 + threadIdx.x;
  int stride = gridDim.x * 256;
  float s = 0.f;
  for (; i < na4 + nb4; i += stride) {
    float4 v = (i < na4) ? A[i] : B[i - na4];
    s += v.x * v.x + v.y * v.y + v.z * v.z + v.w * v.w;
  }
  for (int off = 32; off; off >>= 1) s += __shfl_down(s, off);
  __shared__ float part[4];
  if ((threadIdx.x & 63) == 0) part[threadIdx.x >> 6] = s;
  __syncthreads();
  if (threadIdx.x == 0) atomicAdd(out, part[0] + part[1] + part[2] + part[3]);
}

// ---------------- final combine (1 thread) ----------------
__global__ void k_finish(const float* __restrict__ scal, float* __restrict__ out) {
  float neg_score = scal[SC_NLU] / (float)BATCH + scal[SC_NLI] / (float)(2 * BATCH);
  float pos_score = scal[SC_POSU] / (float)BATCH + scal[SC_POSI] / (float)(2 * BATCH);
  float loss_s = -pos_score + neg_score;
  float loss_r = scal[SC_BPR] / (float)BATCH;
  float ls = 0.2f * loss_s;
  float reg = 1e-5f * scal[SC_SUMSQ];
  out[0] = loss_r + ls + reg;
  out[1] = loss_r;
  out[2] = ls;
}

extern "C" void kernel_launch(void* const* d_in, const int* in_sizes, int n_in,
                              void* d_out, int out_size, void* d_ws, size_t ws_size,
                              hipStream_t stream) {
  const float* Eu0   = (const float*)d_in[0];
  const float* Ei0   = (const float*)d_in[1];
  const float* umuls = (const float*)d_in[2];
  const float* vmuls = (const float*)d_in[3];
  const float* ut    = (const float*)d_in[4];
  const float* vt    = (const float*)d_in[5];
  const float* adj_vals = (const float*)d_in[6];
  const int* adj_rows = (const int*)d_in[7];
  const int* adj_cols = (const int*)d_in[8];
  const int* uids = (const int*)d_in[9];
  const int* pos  = (const int*)d_in[10];
  const int* neg  = (const int*)d_in[11];
  float* out = (float*)d_out;

  char* w = (char*)d_ws;
  size_t off = 0;
  auto alloc = [&](size_t bytes) -> void* {
    void* p = w + off;
    off = (off + bytes + 255) & ~(size_t)255;
    return p;
  };
  int2* epu_raw = (int2*)alloc(sizeof(int2) * NNZ);
  int2* epi_raw = (int2*)alloc(sizeof(int2) * NNZ);
  int2* ep_u = (int2*)alloc(sizeof(int2) * NNZ);
  int2* ep_i = (int2*)alloc(sizeof(int2) * NNZ);
  int* cnt2d_u = (int*)alloc(sizeof(int) * N2D_U);
  int* cnt2d_i = (int*)alloc(sizeof(int) * N2D_I);
  int* row_ptr = (int*)alloc(sizeof(int) * (N_USERS + 1));
  int* col_ptr = (int*)alloc(sizeof(int) * (N_ITEMS + 1));
  bf16* Eu0bf = (bf16*)alloc(sizeof(bf16) * N_USERS * DIM);
  bf16* Ei0bf = (bf16*)alloc(sizeof(bf16) * N_ITEMS * DIM);
  bf16* Zu1bf = (bf16*)alloc(sizeof(bf16) * N_USERS * DIM);
  bf16* Zi1bf = (bf16*)alloc(sizeof(bf16) * N_ITEMS * DIM);
  bf16* sEubf = (bf16*)alloc(sizeof(bf16) * N_USERS * DIM);
  bf16* sEibf = (bf16*)alloc(sizeof(bf16) * N_ITEMS * DIM);
  int* bsum_u = (int*)alloc(sizeof(int) * 64);
  int* boff_u = (int*)alloc(sizeof(int) * 64);
  int* bsum_i = (int*)alloc(sizeof(int) * 64);
  int* boff_i = (int*)alloc(sizeof(int) * 64);
  // zero-init region: Wu, Wi, Su, Si, scal (contiguous; one memset)
  char* zbase = (char*)(w + off);
  float* Wu = (float*)alloc(sizeof(float) * QDIM * DIM);
  float* Wi = (float*)alloc(sizeof(float) * QDIM * DIM);
  float* Su = (float*)alloc(sizeof(float) * BATCH);
  float* Si = (float*)alloc(sizeof(float) * 2 * BATCH);
  float* scal = (float*)alloc(sizeof(float) * 8);
  size_t zlen = (size_t)((char*)(w + off) - zbase);
  bf16* Gbf = (bf16*)alloc(sizeof(bf16) * 3 * BATCH * DIM);

  // folded dropout keys: fold_in(key(42), idx) for idx = 0..3
  uint32_t mk[4][2];
  for (uint32_t i = 0; i < 4; ++i) tf2x32(0u, 42u, 0u, i, mk[i][0], mk[i][1]);

  hipMemsetAsync(zbase, 0, zlen, stream);

  // build: bucket counts -> scans -> partition -> per-bucket sort
  k_bcount<<<NBLK, 256, 0, stream>>>(adj_rows, adj_cols, cnt2d_u, cnt2d_i);
  k_tobf2<<<(N_USERS + N_ITEMS) * DIM / 4 / 256, 256, 0, stream>>>(
      (const float4*)Eu0, (const float4*)Ei0, (ushort4*)Eu0bf, (ushort4*)Ei0bf);
  k_bsum2<<<NBU + NBI, 256, 0, stream>>>(cnt2d_u, cnt2d_i, bsum_u, bsum_i);
  k_bscan2<<<2, 64, 0, stream>>>(bsum_u, bsum_i, boff_u, boff_i);
  k_scan32<<<NBU + NBI, 256, 0, stream>>>(cnt2d_u, cnt2d_i, boff_u, boff_i);
  k_part<<<NBLK, 256, 0, stream>>>(adj_rows, adj_cols, adj_vals, cnt2d_u, cnt2d_i,
                                   epu_raw, epi_raw,
                                   mk[0][0], mk[0][1], mk[2][0], mk[2][1],
                                   mk[1][0], mk[1][1], mk[3][0], mk[3][1]);
  k_csort2<<<NBKT_U + NBKT_I, 256, 0, stream>>>(epu_raw, cnt2d_u, ep_u, row_ptr,
                                                epi_raw, cnt2d_i, ep_i, col_ptr);

  // layer 0: Zu1 = dropA @ Ei0, Zi1 = dropA^T @ Eu0 (merged)
  k_spmm2<0><<<(N_USERS + N_ITEMS) * 64 / 256, 256, 0, stream>>>(
      row_ptr, ep_u, Ei0bf, nullptr, nullptr, Zu1bf,
      col_ptr, ep_i, Eu0bf, nullptr, nullptr, Zi1bf);
  k_wred2<<<512, 256, 0, stream>>>(Ei0bf, vt, Wu, Eu0bf, ut, Wi);

  // layer 1: sE = E0 + Z1 + dropA @ Z1(other side) (merged)
  k_spmm2<1><<<(N_USERS + N_ITEMS) * 64 / 256, 256, 0, stream>>>(
      row_ptr, ep_u, Zi1bf, Eu0, Zu1bf, sEubf,
      col_ptr, ep_i, Zu1bf, Ei0, Zi1bf, sEibf);
  k_wred2<<<512, 256, 0, stream>>>(Zi1bf, vt, Wu, Zu1bf, ut, Wi);

  // batch prep + fused pos/BPR dot products
  k_prep_dots<<<(3 * BATCH * 64) / 256, 256, 0, stream>>>(uids, pos, neg, Eu0, Ei0,
                                                          umuls, vmuls, sEubf, sEibf,
                                                          Wu, Wi, Gbf, scal);

  // InfoNCE denominators (merged users+items)
  k_negsum2<<<1024, 256, 0, stream>>>(Gbf, sEubf, Su, sEibf, Si);

  // L2 reg (merged, vectorized)
  k_sumsq2<<<2048, 256, 0, stream>>>((const float4*)Eu0, N_USERS * DIM / 4,
                                     (const float4*)Ei0, N_ITEMS * DIM / 4,
                                     scal + SC_SUMSQ);

  // parallel log-sum + final combine
  k_logsum<<<(3 * BATCH + 255) / 256, 256, 0, stream>>>(Su, Si, scal);
  k_finish<<<1, 1, 0, stream>>>(scal, out);
}

// Round 11
// 424.918 us; speedup vs baseline: 1.4778x; 1.1912x over previous
//
#include <hip/hip_runtime.h>
#include <hip/hip_bf16.h>
#include <stdint.h>

#define N_USERS 100000
#define N_ITEMS 50000
#define DIM     64
#define QDIM    5
#define NNZ     1000000
#define BATCH   1024
#define HALF_NNZ (NNZ/2)

#define RB      128                       // rows per bucket
#define NBKT_U  ((N_USERS + RB - 1) / RB) // 782
#define NBKT_I  ((N_ITEMS + RB - 1) / RB) // 391
#define NBLK    256                       // partition blocks
#define EPB2    ((HALF_NNZ + NBLK - 1) / NBLK) // 1954 edge-PAIRS per block
#define SC_E    4096                      // elements per scan block (256 thr x 16)
#define N2D_U   (NBKT_U * NBLK)           // 200192
#define N2D_I   (NBKT_I * NBLK)           // 100096
#define NBU     ((N2D_U + SC_E - 1) / SC_E) // 49
#define NBI     ((N2D_I + SC_E - 1) / SC_E) // 25
#define UBLK    (N_USERS * 64 / 256)      // 25000 user spmm blocks
#define CSCAP   3072                      // csort LDS edge capacity (24 KB)
#define WRB     512                       // wred blocks per side

typedef __hip_bfloat16 bf16;
typedef __attribute__((ext_vector_type(8))) short bf16x8;
typedef __attribute__((ext_vector_type(4))) float f32x4;

// scalar accumulator slots: [0]=sumsq [1]=posu [2]=posi [3]=bpr [4]=nlu [5]=nli
#define SC_SUMSQ 0
#define SC_POSU  1
#define SC_POSI  2
#define SC_BPR   3
#define SC_NLU   4
#define SC_NLI   5

// ---------------- threefry2x32 (exact JAX block) ----------------
__host__ __device__ inline void tf2x32(uint32_t k0, uint32_t k1,
                                       uint32_t x0, uint32_t x1,
                                       uint32_t& o0, uint32_t& o1) {
  uint32_t ks2 = k0 ^ k1 ^ 0x1BD11BDAu;
  x0 += k0; x1 += k1;
#define TF_R(r) { x0 += x1; x1 = (x1 << (r)) | (x1 >> (32 - (r))); x1 ^= x0; }
  TF_R(13) TF_R(15) TF_R(26) TF_R(6)
  x0 += k1; x1 += ks2 + 1u;
  TF_R(17) TF_R(29) TF_R(16) TF_R(24)
  x0 += ks2; x1 += k0 + 2u;
  TF_R(13) TF_R(15) TF_R(26) TF_R(6)
  x0 += k0; x1 += k1 + 3u;
  TF_R(17) TF_R(29) TF_R(16) TF_R(24)
  x0 += k1; x1 += ks2 + 4u;
  TF_R(13) TF_R(15) TF_R(26) TF_R(6)
  x0 += ks2; x1 += k0 + 5u;
#undef TF_R
  o0 = x0; o1 = x1;
}

__device__ __forceinline__ float mask_from_bits(uint32_t bits) {
  float f = __uint_as_float((bits >> 9) | 0x3f800000u) - 1.0f;
  return (f < 0.75f) ? (1.0f / 0.75f) : 0.0f;
}

__device__ __forceinline__ uint32_t f2bfbits(float f) {
  bf16 h = __float2bfloat16(f);
  return (uint32_t)(*reinterpret_cast<unsigned short*>(&h));
}

// ---------------- bucket counting (edge pairs, matches k_part) ----------------
__global__ __launch_bounds__(256) void k_bcount(const int* __restrict__ rows,
                                                const int* __restrict__ cols,
                                                int* __restrict__ cnt_u,
                                                int* __restrict__ cnt_i) {
  __shared__ int hu[NBKT_U];
  __shared__ int hv[NBKT_I];
  for (int i = threadIdx.x; i < NBKT_U; i += 256) hu[i] = 0;
  for (int i = threadIdx.x; i < NBKT_I; i += 256) hv[i] = 0;
  __syncthreads();
  int beg = blockIdx.x * EPB2, end = min(beg + EPB2, HALF_NNZ);
  for (int i = beg + threadIdx.x; i < end; i += 256) {
    atomicAdd(&hu[rows[i] >> 7], 1);
    atomicAdd(&hu[rows[i + HALF_NNZ] >> 7], 1);
    atomicAdd(&hv[cols[i] >> 7], 1);
    atomicAdd(&hv[cols[i + HALF_NNZ] >> 7], 1);
  }
  __syncthreads();
  for (int i = threadIdx.x; i < NBKT_U; i += 256) cnt_u[i * NBLK + blockIdx.x] = hu[i];
  for (int i = threadIdx.x; i < NBKT_I; i += 256) cnt_i[i * NBLK + blockIdx.x] = hv[i];
}

// ---------------- merged hierarchical scan (user + item) ----------------
__global__ __launch_bounds__(256) void k_bsum2(const int* __restrict__ cnt_u,
                                               const int* __restrict__ cnt_i,
                                               int* __restrict__ bsum_u,
                                               int* __restrict__ bsum_i) {
  const int* cnt; int n, b; int* bsum;
  if (blockIdx.x < NBU) { cnt = cnt_u; n = N2D_U; b = blockIdx.x; bsum = bsum_u; }
  else { cnt = cnt_i; n = N2D_I; b = blockIdx.x - NBU; bsum = bsum_i; }
  int base = b * SC_E + threadIdx.x * 16;
  int s = 0;
#pragma unroll
  for (int j = 0; j < 16; ++j) { int i = base + j; if (i < n) s += cnt[i]; }
  for (int off = 32; off; off >>= 1) s += __shfl_down(s, off);
  __shared__ int ws[4];
  if ((threadIdx.x & 63) == 0) ws[threadIdx.x >> 6] = s;
  __syncthreads();
  if (threadIdx.x == 0) bsum[b] = ws[0] + ws[1] + ws[2] + ws[3];
}

__global__ __launch_bounds__(64) void k_bscan2(const int* __restrict__ bsum_u,
                                               const int* __restrict__ bsum_i,
                                               int* __restrict__ boff_u,
                                               int* __restrict__ boff_i) {
  const int* bsum; int nb; int* boff;
  if (blockIdx.x == 0) { bsum = bsum_u; nb = NBU; boff = boff_u; }
  else { bsum = bsum_i; nb = NBI; boff = boff_i; }
  int lane = threadIdx.x;
  int v = (lane < nb) ? bsum[lane] : 0;
  int incl = v;
  for (int off = 1; off < 64; off <<= 1) {
    int t = __shfl_up(incl, off);
    if (lane >= off) incl += t;
  }
  if (lane < nb) boff[lane] = incl - v;
}

// in-place exclusive scan (ptr aliases cnt; per-thread chunks disjoint)
__global__ __launch_bounds__(256) void k_scan32(int* __restrict__ cnt_u,
                                                int* __restrict__ cnt_i,
                                                const int* __restrict__ boff_u,
                                                const int* __restrict__ boff_i) {
  int* cnt; int n, b; const int* boff;
  if (blockIdx.x < NBU) { cnt = cnt_u; n = N2D_U; b = blockIdx.x; boff = boff_u; }
  else { cnt = cnt_i; n = N2D_I; b = blockIdx.x - NBU; boff = boff_i; }
  int base = b * SC_E + threadIdx.x * 16;
  int c[16]; int s = 0;
#pragma unroll
  for (int j = 0; j < 16; ++j) { int i = base + j; c[j] = (i < n) ? cnt[i] : 0; s += c[j]; }
  int lane = threadIdx.x & 63, wid = threadIdx.x >> 6;
  int incl = s;
  for (int off = 1; off < 64; off <<= 1) {
    int t = __shfl_up(incl, off);
    if (lane >= off) incl += t;
  }
  __shared__ int wsum[4];
  if (lane == 63) wsum[wid] = incl;
  __syncthreads();
  int wpre = 0;
  for (int k = 0; k < wid; ++k) wpre += wsum[k];
  int run = boff[b] + wpre + (incl - s);
#pragma unroll
  for (int j = 0; j < 16; ++j) {
    int i = base + j;
    if (i < n) { cnt[i] = run; run += c[j]; }
  }
}

// ---------------- partition (edge pairs: both threefry outputs used) ----------
// payload int2: x = (local_row<<17)|col17, y = (bf16(v_layer1)<<16)|bf16(v_layer0)
__global__ __launch_bounds__(256) void k_part(const int* __restrict__ rows,
                                              const int* __restrict__ cols,
                                              const float* __restrict__ adj_vals,
                                              const int* __restrict__ off_u,
                                              const int* __restrict__ off_i,
                                              int2* __restrict__ ep_u,
                                              int2* __restrict__ ep_i,
                                              uint32_t a0, uint32_t a1,
                                              uint32_t b0, uint32_t b1,
                                              uint32_t c0, uint32_t c1,
                                              uint32_t d0, uint32_t d1) {
  __shared__ int cu[NBKT_U];
  __shared__ int ci[NBKT_I];
  for (int i = threadIdx.x; i < NBKT_U; i += 256) cu[i] = off_u[i * NBLK + blockIdx.x];
  for (int i = threadIdx.x; i < NBKT_I; i += 256) ci[i] = off_i[i * NBLK + blockIdx.x];
  __syncthreads();
  int beg = blockIdx.x * EPB2, end = min(beg + EPB2, HALF_NNZ);
  for (int i = beg + threadIdx.x; i < end; i += 256) {
    int e2 = i + HALF_NNZ;
    int rA = rows[i], cA = cols[i];
    int rB = rows[e2], cB = cols[e2];
    float vA = adj_vals[i], vB = adj_vals[e2];
    uint32_t mA0, mA1, mB0, mB1, mC0, mC1, mD0, mD1;
    tf2x32(a0, a1, (uint32_t)i, (uint32_t)e2, mA0, mA1);  // user L0
    tf2x32(b0, b1, (uint32_t)i, (uint32_t)e2, mB0, mB1);  // user L1
    tf2x32(c0, c1, (uint32_t)i, (uint32_t)e2, mC0, mC1);  // item L0
    tf2x32(d0, d1, (uint32_t)i, (uint32_t)e2, mD0, mD1);  // item L1
    // edge i
    {
      uint32_t u0 = f2bfbits(vA * mask_from_bits(mA0));
      uint32_t u1 = f2bfbits(vA * mask_from_bits(mB0));
      uint32_t i0 = f2bfbits(vA * mask_from_bits(mC0));
      uint32_t i1 = f2bfbits(vA * mask_from_bits(mD0));
      int pu = atomicAdd(&cu[rA >> 7], 1);
      ep_u[pu] = make_int2(((rA & 127) << 17) | cA, (int)((u1 << 16) | u0));
      int pi = atomicAdd(&ci[cA >> 7], 1);
      ep_i[pi] = make_int2(((cA & 127) << 17) | rA, (int)((i1 << 16) | i0));
    }
    // edge i + HALF_NNZ
    {
      uint32_t u0 = f2bfbits(vB * mask_from_bits(mA1));
      uint32_t u1 = f2bfbits(vB * mask_from_bits(mB1));
      uint32_t i0 = f2bfbits(vB * mask_from_bits(mC1));
      uint32_t i1 = f2bfbits(vB * mask_from_bits(mD1));
      int pu = atomicAdd(&cu[rB >> 7], 1);
      ep_u[pu] = make_int2(((rB & 127) << 17) | cB, (int)((u1 << 16) | u0));
      int pi = atomicAdd(&ci[cB >> 7], 1);
      ep_i[pi] = make_int2(((cB & 127) << 17) | rB, (int)((i1 << 16) | i0));
    }
  }
}

// ---------------- merged per-bucket counting sort (LDS edge buffer) -----------
__global__ __launch_bounds__(256) void k_csort2(const int2* __restrict__ epu_raw,
                                                const int* __restrict__ cnt2d_u,
                                                int2* __restrict__ ep_u,
                                                int* __restrict__ row_ptr,
                                                const int2* __restrict__ epi_raw,
                                                const int* __restrict__ cnt2d_i,
                                                int2* __restrict__ ep_i,
                                                int* __restrict__ col_ptr) {
  const int2* ep_raw; const int* cnt2d; int2* ep_srt; int* rp; int nrows, nbkt, b;
  if (blockIdx.x < NBKT_U) {
    b = blockIdx.x; ep_raw = epu_raw; cnt2d = cnt2d_u; ep_srt = ep_u;
    rp = row_ptr; nrows = N_USERS; nbkt = NBKT_U;
  } else {
    b = blockIdx.x - NBKT_U; ep_raw = epi_raw; cnt2d = cnt2d_i; ep_srt = ep_i;
    rp = col_ptr; nrows = N_ITEMS; nbkt = NBKT_I;
  }
  int beg = cnt2d[b * NBLK];
  int end = (b + 1 < nbkt) ? cnt2d[(b + 1) * NBLK] : NNZ;
  __shared__ int2 ebuf[CSCAP];
  __shared__ int cnt[RB];
  __shared__ int loff[RB];
  __shared__ int lcur[RB];
  for (int i = threadIdx.x; i < RB; i += 256) cnt[i] = 0;
  __syncthreads();
  for (int k = beg + threadIdx.x; k < end; k += 256) {
    int2 p = ep_raw[k];
    int li = k - beg;
    if (li < CSCAP) ebuf[li] = p;
    atomicAdd(&cnt[(p.x >> 17) & 127], 1);
  }
  __syncthreads();
  if (threadIdx.x < 64) {
    int l = threadIdx.x;
    int e0 = cnt[2 * l], e1 = cnt[2 * l + 1];
    int s = e0 + e1;
    int incl = s;
    for (int off = 1; off < 64; off <<= 1) {
      int t = __shfl_up(incl, off);
      if (l >= off) incl += t;
    }
    int excl = incl - s;
    loff[2 * l] = excl;
    loff[2 * l + 1] = excl + e0;
  }
  __syncthreads();
  for (int r = threadIdx.x; r < RB; r += 256) {
    lcur[r] = beg + loff[r];
    int row = b * RB + r;
    if (row < nrows) rp[row] = beg + loff[r];
  }
  if (b == 0 && threadIdx.x == 0) rp[nrows] = NNZ;
  __syncthreads();
  for (int k = beg + threadIdx.x; k < end; k += 256) {
    int li = k - beg;
    int2 p = (li < CSCAP) ? ebuf[li] : ep_raw[k];
    int pos = atomicAdd(&lcur[(p.x >> 17) & 127], 1);
    ep_srt[pos] = p;
  }
}

// ---------------- merged f32 -> bf16 convert ----------------
__global__ __launch_bounds__(256) void k_tobf2(const float4* __restrict__ Eu,
                                               const float4* __restrict__ Ei,
                                               ushort4* __restrict__ ou,
                                               ushort4* __restrict__ oi) {
  int i = blockIdx.x * 256 + threadIdx.x;
  const int nu4 = N_USERS * DIM / 4;
  float4 v; ushort4* o;
  if (i < nu4) { v = Eu[i]; o = ou + i; }
  else { v = Ei[i - nu4]; o = oi + (i - nu4); }
  ushort4 r;
  r.x = (unsigned short)f2bfbits(v.x);
  r.y = (unsigned short)f2bfbits(v.y);
  r.z = (unsigned short)f2bfbits(v.z);
  r.w = (unsigned short)f2bfbits(v.w);
  *o = r;
}

// ---------------- merged SpMM: 8-deep NAMED-REGISTER pipelined gathers -------
// blocks [0,UBLK): user rows; rest: item rows
// LAYER 0: out = bf16(dropA @ X).  LAYER 1: out = bf16(E0 + Z1 + dropA @ X)
template<int LAYER>
__global__ __launch_bounds__(256) void k_spmm2(const int* __restrict__ row_ptr,
                                               const int2* __restrict__ ep_u,
                                               const bf16* __restrict__ Xu,
                                               const float* __restrict__ Eu0,
                                               const bf16* __restrict__ Zu1,
                                               bf16* __restrict__ outU,
                                               const int* __restrict__ col_ptr,
                                               const int2* __restrict__ ep_i,
                                               const bf16* __restrict__ Xi,
                                               const float* __restrict__ Ei0,
                                               const bf16* __restrict__ Zi1,
                                               bf16* __restrict__ outI) {
  const int* ptr; const int2* ep; const bf16* X; const float* E0; const bf16* Z1; bf16* o;
  int wbase;
  if (blockIdx.x < UBLK) {
    ptr = row_ptr; ep = ep_u; X = Xu; E0 = Eu0; Z1 = Zu1; o = outU;
    wbase = blockIdx.x * 4;
  } else {
    ptr = col_ptr; ep = ep_i; X = Xi; E0 = Ei0; Z1 = Zi1; o = outI;
    wbase = (blockIdx.x - UBLK) * 4;
  }
  int lane = threadIdx.x & 63;
  int w = __builtin_amdgcn_readfirstlane(wbase + (threadIdx.x >> 6));
  int beg = ptr[w], end = ptr[w + 1];          // uniform -> s_load
  float acc = 0.f;
  int k = beg;
  int kend8 = beg + ((end - beg) & ~7);        // full chunks of 8, branchless body
#define VB_(y) __uint_as_float(LAYER ? ((uint32_t)(y) & 0xFFFF0000u) : ((uint32_t)(y) << 16))
#define XG_(p) __bfloat162float(X[(size_t)((p).x & 0x1FFFF) * DIM + lane])
  for (; k < kend8; k += 8) {
    int2 p0 = ep[k + 0]; int2 p1 = ep[k + 1]; int2 p2 = ep[k + 2]; int2 p3 = ep[k + 3];
    int2 p4 = ep[k + 4]; int2 p5 = ep[k + 5]; int2 p6 = ep[k + 6]; int2 p7 = ep[k + 7];
    float x0 = XG_(p0); float x1 = XG_(p1); float x2 = XG_(p2); float x3 = XG_(p3);
    float x4 = XG_(p4); float x5 = XG_(p5); float x6 = XG_(p6); float x7 = XG_(p7);
    acc += VB_(p0.y) * x0; acc += VB_(p1.y) * x1;
    acc += VB_(p2.y) * x2; acc += VB_(p3.y) * x3;
    acc += VB_(p4.y) * x4; acc += VB_(p5.y) * x5;
    acc += VB_(p6.y) * x6; acc += VB_(p7.y) * x7;
  }
  for (; k < end; ++k) {
    int2 p = ep[k];
    acc += VB_(p.y) * XG_(p);
  }
#undef VB_
#undef XG_
  size_t off = (size_t)w * DIM + lane;
  if (LAYER == 0) {
    o[off] = __float2bfloat16(acc);
  } else {
    float s = E0[off] + __bfloat162float(Z1[off]) + acc;
    o[off] = __float2bfloat16(s);
  }
}

// ---------------- merged W reductions: unroll-4 + LDS reduce + 1 atomic/blk --
__global__ __launch_bounds__(256) void k_wred2(const bf16* __restrict__ Xi_tab,
                                               const float* __restrict__ vt,
                                               float* __restrict__ Wu,
                                               const bf16* __restrict__ Xu_tab,
                                               const float* __restrict__ ut,
                                               float* __restrict__ Wi) {
  const bf16* X; const float* Vt; float* W; int n, b;
  if (blockIdx.x < WRB) { X = Xi_tab; Vt = vt; W = Wu; n = N_ITEMS; b = blockIdx.x; }
  else { X = Xu_tab; Vt = ut; W = Wi; n = N_USERS; b = blockIdx.x - WRB; }
  int lane = threadIdx.x & 63, wid = threadIdx.x >> 6;
  int w0 = b * 4 + wid;
  const int nw = WRB * 4;   // 2048 waves per side
  float acc[QDIM] = {0.f, 0.f, 0.f, 0.f, 0.f};
  int i = w0;
  for (; i + 3 * nw < n; i += 4 * nw) {
    int i0 = i, i1 = i + nw, i2 = i + 2 * nw, i3 = i + 3 * nw;
    float x0 = __bfloat162float(X[(size_t)i0 * DIM + lane]);
    float x1 = __bfloat162float(X[(size_t)i1 * DIM + lane]);
    float x2 = __bfloat162float(X[(size_t)i2 * DIM + lane]);
    float x3 = __bfloat162float(X[(size_t)i3 * DIM + lane]);
#pragma unroll
    for (int q = 0; q < QDIM; ++q) {
      acc[q] += Vt[(size_t)q * n + i0] * x0 + Vt[(size_t)q * n + i1] * x1 +
                Vt[(size_t)q * n + i2] * x2 + Vt[(size_t)q * n + i3] * x3;
    }
  }
  for (; i < n; i += nw) {
    float x = __bfloat162float(X[(size_t)i * DIM + lane]);
#pragma unroll
    for (int q = 0; q < QDIM; ++q) acc[q] += Vt[(size_t)q * n + i] * x;
  }
  __shared__ float red[4][QDIM][DIM];
#pragma unroll
  for (int q = 0; q < QDIM; ++q) red[wid][q][lane] = acc[q];
  __syncthreads();
  if (wid == 0) {
#pragma unroll
    for (int q = 0; q < QDIM; ++q) {
      float s = red[0][q][lane] + red[1][q][lane] + red[2][q][lane] + red[3][q][lane];
      atomicAdd(&W[q * DIM + lane], s);
    }
  }
}

// ---------------- batch-row prep + fused dot products ----------------
__global__ __launch_bounds__(256) void k_prep_dots(const int* __restrict__ uids,
                                                   const int* __restrict__ pos,
                                                   const int* __restrict__ neg,
                                                   const float* __restrict__ Eu0,
                                                   const float* __restrict__ Ei0,
                                                   const float* __restrict__ umuls,
                                                   const float* __restrict__ vmuls,
                                                   const bf16* __restrict__ sEubf,
                                                   const bf16* __restrict__ sEibf,
                                                   const float* __restrict__ Wu,
                                                   const float* __restrict__ Wi,
                                                   bf16* __restrict__ Gbf,
                                                   float* __restrict__ scal) {
  int row = (blockIdx.x * 256 + threadIdx.x) >> 6;
  int lane = threadIdx.x & 63;
  if (row >= 3 * BATCH) return;
  if (row < BATCH) {
    int u = uids[row];
    size_t base = (size_t)u * DIM + lane;
    float g = Eu0[base];
#pragma unroll
    for (int q = 0; q < QDIM; ++q) g += umuls[u * QDIM + q] * Wu[q * DIM + lane];
    Gbf[row * DIM + lane] = __float2bfloat16(g);
    float se = __bfloat162float(sEubf[base]);
    float sp = __bfloat162float(sEibf[(size_t)pos[row] * DIM + lane]);
    float sn = __bfloat162float(sEibf[(size_t)neg[row] * DIM + lane]);
    float d = g * se, dp = se * sp, dn = se * sn;
    for (int off = 32; off; off >>= 1) {
      d += __shfl_down(d, off);
      dp += __shfl_down(dp, off);
      dn += __shfl_down(dn, off);
    }
    if (lane == 0) {
      float posu = fminf(fmaxf(d * 5.0f, -5.f), 5.f);
      float diff = dp - dn;
      float bpr = fmaxf(-diff, 0.f) + log1pf(expf(-fabsf(diff)));
      atomicAdd(&scal[SC_POSU], posu);
      atomicAdd(&scal[SC_BPR], bpr);
    }
  } else {
    int r = row - BATCH;
    int it = (r < BATCH) ? pos[r] : neg[r - BATCH];
    size_t base = (size_t)it * DIM + lane;
    float g = Ei0[base];
#pragma unroll
    for (int q = 0; q < QDIM; ++q) g += vmuls[it * QDIM + q] * Wi[q * DIM + lane];
    Gbf[row * DIM + lane] = __float2bfloat16(g);
    float se = __bfloat162float(sEibf[base]);
    float d = g * se;
    for (int off = 32; off; off >>= 1) d += __shfl_down(d, off);
    if (lane == 0)
      atomicAdd(&scal[SC_POSI], fminf(fmaxf(d * 5.0f, -5.f), 5.f));
  }
}

// ---------------- merged InfoNCE denominator (users + items) ----------------
__global__ __launch_bounds__(256) void k_negsum2(const bf16* __restrict__ Gbf,
                                                 const bf16* __restrict__ sEubf,
                                                 float* __restrict__ Su,
                                                 const bf16* __restrict__ sEibf,
                                                 float* __restrict__ Si) {
  const bf16* G; const bf16* SE; float* S; int n, n_bblk, uch, bid;
  if (blockIdx.x < 512) {
    G = Gbf; SE = sEubf; S = Su; n = N_USERS; n_bblk = 4; uch = 128; bid = blockIdx.x;
  } else {
    G = Gbf + (size_t)BATCH * DIM; SE = sEibf; S = Si; n = N_ITEMS;
    n_bblk = 8; uch = 64; bid = blockIdx.x - 512;
  }
  int bblk = bid % n_bblk;
  int uc = bid / n_bblk;
  int wid = threadIdx.x >> 6;
  int lane = threadIdx.x & 63;
  int b0 = bblk * 256 + wid * 64;
  int fr = lane & 15, fq = lane >> 4;

  bf16x8 a0[4], a1[4];
#pragma unroll
  for (int t = 0; t < 4; ++t) {
    a0[t] = *(const bf16x8*)(G + (size_t)(b0 + t * 16 + fr) * DIM + fq * 8);
    a1[t] = *(const bf16x8*)(G + (size_t)(b0 + t * 16 + fr) * DIM + 32 + fq * 8);
  }

  int tiles = n / 16;
  int per = ((tiles + uch - 1) / uch) * 16;
  int u_lo = uc * per;
  int u_hi = min(n, u_lo + per);

  float racc[16];
#pragma unroll
  for (int j = 0; j < 16; ++j) racc[j] = 0.f;
  const float invT = 5.0f;
  for (int u0 = u_lo; u0 < u_hi; u0 += 16) {
    bf16x8 bfr0 = *(const bf16x8*)(SE + (size_t)(u0 + fr) * DIM + fq * 8);
    bf16x8 bfr1 = *(const bf16x8*)(SE + (size_t)(u0 + fr) * DIM + 32 + fq * 8);
#pragma unroll
    for (int t = 0; t < 4; ++t) {
      f32x4 c = {0.f, 0.f, 0.f, 0.f};
      c = __builtin_amdgcn_mfma_f32_16x16x32_bf16(a0[t], bfr0, c, 0, 0, 0);
      c = __builtin_amdgcn_mfma_f32_16x16x32_bf16(a1[t], bfr1, c, 0, 0, 0);
#pragma unroll
      for (int j = 0; j < 4; ++j) racc[t * 4 + j] += __expf(c[j] * invT);
    }
  }
#pragma unroll
  for (int t = 0; t < 4; ++t) {
#pragma unroll
    for (int j = 0; j < 4; ++j) {
      float v = racc[t * 4 + j];
      v += __shfl_xor(v, 1);
      v += __shfl_xor(v, 2);
      v += __shfl_xor(v, 4);
      v += __shfl_xor(v, 8);
      if (fr == 0) atomicAdd(&S[b0 + t * 16 + fq * 4 + j], v);
    }
  }
}

// ---------------- parallel log-sum of Su/Si ----------------
__global__ __launch_bounds__(256) void k_logsum(const float* __restrict__ Su,
                                                const float* __restrict__ Si,
                                                float* __restrict__ scal) {
  int i = blockIdx.x * 256 + threadIdx.x;
  float lu = 0.f, li = 0.f;
  if (i < BATCH) lu = logf(Su[i] + 1e-8f);
  else if (i < 3 * BATCH) li = logf(Si[i - BATCH] + 1e-8f);
  for (int off = 32; off; off >>= 1) {
    lu += __shfl_down(lu, off);
    li += __shfl_down(li, off);
  }
  __shared__ float pu[4], pi_[4];
  if ((threadIdx.x & 63) == 0) { pu[threadIdx.x >> 6] = lu; pi_[threadIdx.x >> 6] = li; }
  __syncthreads();
  if (threadIdx.x == 0) {
    atomicAdd(&scal[SC_NLU], pu[0] + pu[1] + pu[2] + pu[3]);
    atomicAdd(&scal[SC_NLI], pi_[0] + pi_[1] + pi_[2] + pi_[3]);
  }
}

// ---------------- merged sum of squares (float4) ----------------
__global__ __launch_bounds__(256) void k_sumsq2(const float4* __restrict__ A, int na4,
                                                const float4* __restrict__ B, int nb4,
                                                float* __restrict__ out) {
  int i = blockIdx.x * 256 + threadIdx.x;
  int stride = gridDim.x * 256;
  float s = 0.f;
  for (; i < na4 + nb4; i += stride) {
    float4 v = (i < na4) ? A[i] : B[i - na4];
    s += v.x * v.x + v.y * v.y + v.z * v.z + v.w * v.w;
  }
  for (int off = 32; off; off >>= 1) s += __shfl_down(s, off);
  __shared__ float part[4];
  if ((threadIdx.x & 63) == 0) part[threadIdx.x >> 6] = s;
  __syncthreads();
  if (threadIdx.x == 0) atomicAdd(out, part[0] + part[1] + part[2] + part[3]);
}

// ---------------- final combine (1 thread) ----------------
__global__ void k_finish(const float* __restrict__ scal, float* __restrict__ out) {
  float neg_score = scal[SC_NLU] / (float)BATCH + scal[SC_NLI] / (float)(2 * BATCH);
  float pos_score = scal[SC_POSU] / (float)BATCH + scal[SC_POSI] / (float)(2 * BATCH);
  float loss_s = -pos_score + neg_score;
  float loss_r = scal[SC_BPR] / (float)BATCH;
  float ls = 0.2f * loss_s;
  float reg = 1e-5f * scal[SC_SUMSQ];
  out[0] = loss_r + ls + reg;
  out[1] = loss_r;
  out[2] = ls;
}

extern "C" void kernel_launch(void* const* d_in, const int* in_sizes, int n_in,
                              void* d_out, int out_size, void* d_ws, size_t ws_size,
                              hipStream_t stream) {
  const float* Eu0   = (const float*)d_in[0];
  const float* Ei0   = (const float*)d_in[1];
  const float* umuls = (const float*)d_in[2];
  const float* vmuls = (const float*)d_in[3];
  const float* ut    = (const float*)d_in[4];
  const float* vt    = (const float*)d_in[5];
  const float* adj_vals = (const float*)d_in[6];
  const int* adj_rows = (const int*)d_in[7];
  const int* adj_cols = (const int*)d_in[8];
  const int* uids = (const int*)d_in[9];
  const int* pos  = (const int*)d_in[10];
  const int* neg  = (const int*)d_in[11];
  float* out = (float*)d_out;

  char* w = (char*)d_ws;
  size_t off = 0;
  auto alloc = [&](size_t bytes) -> void* {
    void* p = w + off;
    off = (off + bytes + 255) & ~(size_t)255;
    return p;
  };
  int2* epu_raw = (int2*)alloc(sizeof(int2) * NNZ);
  int2* epi_raw = (int2*)alloc(sizeof(int2) * NNZ);
  int2* ep_u = (int2*)alloc(sizeof(int2) * NNZ);
  int2* ep_i = (int2*)alloc(sizeof(int2) * NNZ);
  int* cnt2d_u = (int*)alloc(sizeof(int) * N2D_U);
  int* cnt2d_i = (int*)alloc(sizeof(int) * N2D_I);
  int* row_ptr = (int*)alloc(sizeof(int) * (N_USERS + 1));
  int* col_ptr = (int*)alloc(sizeof(int) * (N_ITEMS + 1));
  bf16* Eu0bf = (bf16*)alloc(sizeof(bf16) * N_USERS * DIM);
  bf16* Ei0bf = (bf16*)alloc(sizeof(bf16) * N_ITEMS * DIM);
  bf16* Zu1bf = (bf16*)alloc(sizeof(bf16) * N_USERS * DIM);
  bf16* Zi1bf = (bf16*)alloc(sizeof(bf16) * N_ITEMS * DIM);
  bf16* sEubf = (bf16*)alloc(sizeof(bf16) * N_USERS * DIM);
  bf16* sEibf = (bf16*)alloc(sizeof(bf16) * N_ITEMS * DIM);
  int* bsum_u = (int*)alloc(sizeof(int) * 64);
  int* boff_u = (int*)alloc(sizeof(int) * 64);
  int* bsum_i = (int*)alloc(sizeof(int) * 64);
  int* boff_i = (int*)alloc(sizeof(int) * 64);
  // zero-init region: Wu, Wi, Su, Si, scal (contiguous; one memset)
  char* zbase = (char*)(w + off);
  float* Wu = (float*)alloc(sizeof(float) * QDIM * DIM);
  float* Wi = (float*)alloc(sizeof(float) * QDIM * DIM);
  float* Su = (float*)alloc(sizeof(float) * BATCH);
  float* Si = (float*)alloc(sizeof(float) * 2 * BATCH);
  float* scal = (float*)alloc(sizeof(float) * 8);
  size_t zlen = (size_t)((char*)(w + off) - zbase);
  bf16* Gbf = (bf16*)alloc(sizeof(bf16) * 3 * BATCH * DIM);

  // folded dropout keys: fold_in(key(42), idx) for idx = 0..3
  uint32_t mk[4][2];
  for (uint32_t i = 0; i < 4; ++i) tf2x32(0u, 42u, 0u, i, mk[i][0], mk[i][1]);

  hipMemsetAsync(zbase, 0, zlen, stream);

  // build: bucket counts -> scans -> partition -> per-bucket sort
  k_bcount<<<NBLK, 256, 0, stream>>>(adj_rows, adj_cols, cnt2d_u, cnt2d_i);
  k_tobf2<<<(N_USERS + N_ITEMS) * DIM / 4 / 256, 256, 0, stream>>>(
      (const float4*)Eu0, (const float4*)Ei0, (ushort4*)Eu0bf, (ushort4*)Ei0bf);
  k_bsum2<<<NBU + NBI, 256, 0, stream>>>(cnt2d_u, cnt2d_i, bsum_u, bsum_i);
  k_bscan2<<<2, 64, 0, stream>>>(bsum_u, bsum_i, boff_u, boff_i);
  k_scan32<<<NBU + NBI, 256, 0, stream>>>(cnt2d_u, cnt2d_i, boff_u, boff_i);
  k_part<<<NBLK, 256, 0, stream>>>(adj_rows, adj_cols, adj_vals, cnt2d_u, cnt2d_i,
                                   epu_raw, epi_raw,
                                   mk[0][0], mk[0][1], mk[2][0], mk[2][1],
                                   mk[1][0], mk[1][1], mk[3][0], mk[3][1]);
  k_csort2<<<NBKT_U + NBKT_I, 256, 0, stream>>>(epu_raw, cnt2d_u, ep_u, row_ptr,
                                                epi_raw, cnt2d_i, ep_i, col_ptr);

  // layer 0: Zu1 = dropA @ Ei0, Zi1 = dropA^T @ Eu0 (merged)
  k_spmm2<0><<<(N_USERS + N_ITEMS) * 64 / 256, 256, 0, stream>>>(
      row_ptr, ep_u, Ei0bf, nullptr, nullptr, Zu1bf,
      col_ptr, ep_i, Eu0bf, nullptr, nullptr, Zi1bf);
  k_wred2<<<2 * WRB, 256, 0, stream>>>(Ei0bf, vt, Wu, Eu0bf, ut, Wi);

  // layer 1: sE = E0 + Z1 + dropA @ Z1(other side) (merged)
  k_spmm2<1><<<(N_USERS + N_ITEMS) * 64 / 256, 256, 0, stream>>>(
      row_ptr, ep_u, Zi1bf, Eu0, Zu1bf, sEubf,
      col_ptr, ep_i, Zu1bf, Ei0, Zi1bf, sEibf);
  k_wred2<<<2 * WRB, 256, 0, stream>>>(Zi1bf, vt, Wu, Zu1bf, ut, Wi);

  // batch prep + fused pos/BPR dot products
  k_prep_dots<<<(3 * BATCH * 64) / 256, 256, 0, stream>>>(uids, pos, neg, Eu0, Ei0,
                                                          umuls, vmuls, sEubf, sEibf,
                                                          Wu, Wi, Gbf, scal);

  // InfoNCE denominators (merged users+items)
  k_negsum2<<<1024, 256, 0, stream>>>(Gbf, sEubf, Su, sEibf, Si);

  // L2 reg (merged, vectorized)
  k_sumsq2<<<2048, 256, 0, stream>>>((const float4*)Eu0, N_USERS * DIM / 4,
                                     (const float4*)Ei0, N_ITEMS * DIM / 4,
                                     scal + SC_SUMSQ);

  // parallel log-sum + final combine
  k_logsum<<<(3 * BATCH + 255) / 256, 256, 0, stream>>>(Su, Si, scal);
  k_finish<<<1, 1, 0, stream>>>(scal, out);
}